// Round 10
// baseline (638.246 us; speedup 1.0000x reference)
//
#include <hip/hip_runtime.h>
#include <math.h>

// S=64 seq, B=256 atoms, N=16384, D=128, H=8, HD=16, DFF=2048, NL=6.
// R10: ONE kernel for lin0 + all 6 transformer layers (block b = atom b is
// independent across layers: attention mixes only over s within fixed b).
// x carried in fp32 registers (xres) + f16 LDS (Xs). All-f16 datapath
// (weights + intermediates + mfma_f32_16x16x32_f16). s2s tail unchanged.

typedef _Float16 __attribute__((ext_vector_type(8))) f16x8;
typedef __attribute__((ext_vector_type(4))) float f32x4;
typedef _Float16 __attribute__((ext_vector_type(2))) h16x2;

__device__ __forceinline__ unsigned short f2h(float f) {
  union { _Float16 h; unsigned short s; } x; x.h = (_Float16)f; return x.s;
}
__device__ __forceinline__ float h2f(unsigned short u) {
  union { unsigned short s; _Float16 h; } x; x.s = u; return (float)x.h;
}
__device__ __forceinline__ unsigned packh(float a, float b) {
  return (unsigned)f2h(a) | ((unsigned)f2h(b) << 16);
}
__device__ __forceinline__ float hlo(unsigned u) {
  union { unsigned short s; _Float16 h; } x; x.s = (unsigned short)(u & 0xffff);
  return (float)x.h;
}
__device__ __forceinline__ float hhi(unsigned u) {
  union { unsigned short s; _Float16 h; } x; x.s = (unsigned short)(u >> 16);
  return (float)x.h;
}
__device__ __forceinline__ float fdot2u(unsigned a, unsigned b, float c) {
#if __has_builtin(__builtin_amdgcn_fdot2)
  union U { unsigned u; h16x2 h; };
  U x, y; x.u = a; y.u = b;
  return __builtin_amdgcn_fdot2(x.h, y.h, c, false);
#else
  return c + hlo(a) * hlo(b) + hhi(a) * hhi(b);
#endif
}
__device__ __forceinline__ float sigf(float x) { return 1.f / (1.f + expf(-x)); }

// async 16B global->LDS; LDS base wave-uniform (+ lane*16 implicit).
__device__ __forceinline__ void gl2lds16(const void* g, void* l) {
  __builtin_amdgcn_global_load_lds(
      (const __attribute__((address_space(1))) unsigned int*)g,
      (__attribute__((address_space(3))) unsigned int*)l, 16, 0, 0);
}

// ---------------------------------------------------------------------------
// weight conversion: everything -> f16.
// aiw 294912 | aow 98304 | w1 1572864 | w2 1572864
// | wih 131072 | whh 65536 | mwih 131072   -> total 3866624
// ---------------------------------------------------------------------------
__global__ __launch_bounds__(256) void convw_kernel(
    const float* __restrict__ aiw, const float* __restrict__ aow,
    const float* __restrict__ w1, const float* __restrict__ w2,
    const float* __restrict__ wih, const float* __restrict__ whh,
    const float* __restrict__ mwih,
    unsigned short* __restrict__ o0, unsigned short* __restrict__ o1,
    unsigned short* __restrict__ o2, unsigned short* __restrict__ o3,
    unsigned short* __restrict__ o4, unsigned short* __restrict__ o5,
    unsigned short* __restrict__ o6) {
  int i = blockIdx.x * 256 + threadIdx.x;
  if (i < 294912) {
    o0[i] = f2h(aiw[i]);
  } else if (i < 393216) {
    int j = i - 294912; o1[j] = f2h(aow[j]);
  } else if (i < 1966080) {
    int j = i - 393216; o2[j] = f2h(w1[j]);
  } else if (i < 3538944) {
    int j = i - 1966080; o3[j] = f2h(w2[j]);
  } else if (i < 3670016) {
    int j = i - 3538944; o4[j] = f2h(wih[j]);
  } else if (i < 3735552) {
    int j = i - 3670016; o5[j] = f2h(whh[j]);
  } else {
    int j = i - 3735552; o6[j] = f2h(mwih[j]);
  }
}

// ---------------------------------------------------------------------------
// Fused transformer: block = atom b (256 blocks), 512 threads, 8 waves.
// lin0 prologue -> 6x (qkv -> attention -> Wout+LN1 -> FFN+LN2) -> xb (f16).
// Thread owns cells (row = si*16+fq*4+r, col = w*16+fr); x in xres fp32 regs.
// ---------------------------------------------------------------------------
__global__ __launch_bounds__(512) void trans_kernel(
    const float* __restrict__ data,
    const float* __restrict__ lin0_w, const float* __restrict__ lin0_b,
    const unsigned short* __restrict__ wqkv_a, const float* __restrict__ bqkv_a,
    const unsigned short* __restrict__ wout_a, const float* __restrict__ bout_a,
    const float* __restrict__ ln1g_a, const float* __restrict__ ln1b_a,
    const unsigned short* __restrict__ w1_a, const float* __restrict__ b1_a,
    const unsigned short* __restrict__ w2_a, const float* __restrict__ b2_a,
    const float* __restrict__ ln2g_a, const float* __restrict__ ln2b_a,
    unsigned short* __restrict__ xbo) {
  __shared__ __align__(16) unsigned short Xs[64 * 128];   // 16 KB (x, f16)
  __shared__ __align__(16) unsigned short Ws[256 * 128];  // 64 KB
  __shared__ __align__(16) unsigned short U1[128 * 128];  // 32 KB
  __shared__ __align__(16) unsigned short U2[128 * 128];  // 32 KB
  __shared__ __align__(16) uint4 zchunk;
  __shared__ float psum[8][64], psq[8][64];
  __shared__ float2 stats[64];

  unsigned short* Qs = U1;
  unsigned short* Ks2 = U1 + 8192;
  unsigned short* VT = U2;
  unsigned short* AOs = U2 + 8192;
  unsigned short* Hs = U2;  // FFN (swizzled 128-stride)

  int tid = threadIdx.x, w = tid >> 6, lane = tid & 63;
  int b = blockIdx.x;
  int r4 = lane >> 4, cs = lane & 15;
  int fr = lane & 15, fq = lane >> 4;
  int c = w * 16 + fr;  // this thread's column (0..127)

  if (tid == 0) zchunk = make_uint4(0u, 0u, 0u, 0u);

  // ---- lin0: x = relu(data @ w0^T + b0) -> xres + Xs ----
  float xres[4][4];
  {
    float w00 = lin0_w[c * 3], w01 = lin0_w[c * 3 + 1], w02 = lin0_w[c * 3 + 2];
    float b0c = lin0_b[c];
#pragma unroll
    for (int si = 0; si < 4; si++)
#pragma unroll
      for (int r = 0; r < 4; r++) {
        int row = si * 16 + fq * 4 + r;
        const float* dp = data + (size_t)(row * 256 + b) * 3;
        float v = fmaxf(b0c + dp[0] * w00 + dp[1] * w01 + dp[2] * w02, 0.f);
        xres[si][r] = v;
        Xs[row * 128 + (((c >> 3) ^ (row & 7)) << 3) + (c & 7)] = f2h(v);
      }
  }

  for (int l = 0; l < 6; l++) {
    const unsigned short* wqkv = wqkv_a + (size_t)l * 49152;
    const float* bqkv = bqkv_a + l * 384;
    const unsigned short* wout = wout_a + (size_t)l * 16384;
    const float* bout = bout_a + l * 128;
    const float* ln1g = ln1g_a + l * 128, * ln1b = ln1b_a + l * 128;
    const unsigned short* w1 = w1_a + (size_t)l * 262144;
    const float* b1 = b1_a + l * 2048;
    const unsigned short* w2 = w2_a + (size_t)l * 262144;
    const float* b2 = b2_a + l * 128;
    const float* ln2g = ln2g_a + l * 128, * ln2b = ln2b_a + l * 128;

    // ---- stage Wq+Wk (rows 0..255) ----
#pragma unroll
    for (int i = 0; i < 8; i++) {
      int issue = w * 8 + i;
      int row = issue * 4 + r4;
      int g = cs ^ (row & 7);
      gl2lds16(wqkv + (size_t)row * 128 + g * 8, (char*)Ws + issue * 1024);
    }
    __syncthreads();  // Wqk ready; Xs stable (prologue or prev epilogue+barrier)

    // hoisted x A-fragments (phases 1 and 2)
    f16x8 xfragA[4][4];
#pragma unroll
    for (int ks = 0; ks < 4; ks++)
#pragma unroll
      for (int mi = 0; mi < 4; mi++) {
        int row = mi * 16 + fr;
        int kq = (ks * 4 + fq) ^ (row & 7);
        xfragA[ks][mi] = *(const f16x8*)(Xs + row * 128 + kq * 8);
      }

    // ---- phase 1: Q,K -> Qs/Ks2 ----
    {
      f32x4 acc[4][2];
#pragma unroll
      for (int i = 0; i < 4; i++)
#pragma unroll
        for (int j = 0; j < 2; j++) acc[i][j] = (f32x4){0.f, 0.f, 0.f, 0.f};
#pragma unroll
      for (int ks = 0; ks < 4; ks++) {
        f16x8 bf[2];
#pragma unroll
        for (int ni = 0; ni < 2; ni++) {
          int wr = (w * 2 + ni) * 16 + fr;
          int kq = (ks * 4 + fq) ^ (wr & 7);
          bf[ni] = *(const f16x8*)(Ws + wr * 128 + kq * 8);
        }
#pragma unroll
        for (int mi = 0; mi < 4; mi++)
#pragma unroll
          for (int ni = 0; ni < 2; ni++)
            acc[mi][ni] = __builtin_amdgcn_mfma_f32_16x16x32_f16(
                xfragA[ks][mi], bf[ni], acc[mi][ni], 0, 0, 0);
      }
#pragma unroll
      for (int ni = 0; ni < 2; ni++) {
        int cq = (w * 2 + ni) * 16 + fr;  // 0..255
        float bv = bqkv[cq];
        unsigned short* dst = (cq < 128) ? Qs : Ks2;
        int cc = cq & 127;
#pragma unroll
        for (int mi = 0; mi < 4; mi++)
#pragma unroll
          for (int r = 0; r < 4; r++) {
            int row = mi * 16 + fq * 4 + r;
            dst[row * 128 + (((cc >> 3) ^ (row & 7)) << 3) + (cc & 7)] =
                f2h(acc[mi][ni][r] + bv);
          }
      }
    }
    __syncthreads();

    // ---- stage Wv (rows 256..383) ----
#pragma unroll
    for (int i = 0; i < 4; i++) {
      int issue = w * 4 + i;
      int row = issue * 4 + r4;
      int g = cs ^ (row & 7);
      gl2lds16(wqkv + (size_t)(256 + row) * 128 + g * 8,
               (char*)Ws + issue * 1024);
    }
    __syncthreads();

    // ---- phase 2: V -> VT[feature][s] ----
    {
      f32x4 acc[4];
#pragma unroll
      for (int i = 0; i < 4; i++) acc[i] = (f32x4){0.f, 0.f, 0.f, 0.f};
#pragma unroll
      for (int ks = 0; ks < 4; ks++) {
        f16x8 bf;
        {
          int wr = w * 16 + fr;
          int kq = (ks * 4 + fq) ^ (wr & 7);
          bf = *(const f16x8*)(Ws + wr * 128 + kq * 8);
        }
#pragma unroll
        for (int mi = 0; mi < 4; mi++)
          acc[mi] = __builtin_amdgcn_mfma_f32_16x16x32_f16(xfragA[ks][mi], bf,
                                                           acc[mi], 0, 0, 0);
      }
      float bv = bqkv[256 + c];
#pragma unroll
      for (int mi = 0; mi < 4; mi++)
#pragma unroll
        for (int r = 0; r < 4; r++) {
          int srow = mi * 16 + fq * 4 + r;
          VT[c * 64 + (((srow >> 3) ^ (c & 7)) << 3) + (srow & 7)] =
              f2h(acc[mi][r] + bv);
        }
    }
    __syncthreads();

    // ---- phase 3: per-wave head attention (head h = w), P in Ws ----
    {
      int h = w;
      unsigned short* Pb = Ws + w * 4096;
      f32x4 sc[4][4];
#pragma unroll
      for (int i = 0; i < 4; i++)
#pragma unroll
        for (int j = 0; j < 4; j++) sc[i][j] = (f32x4){0.f, 0.f, 0.f, 0.f};
      {
        f16x8 af[4], bf[4];
#pragma unroll
        for (int mi = 0; mi < 4; mi++) {
          int row = mi * 16 + fr;
          const unsigned short* pa =
              (fq < 2) ? (Qs + row * 128 + (((h * 2 + fq) ^ (row & 7)) << 3))
                       : (const unsigned short*)&zchunk;
          af[mi] = *(const f16x8*)pa;
        }
#pragma unroll
        for (int ti = 0; ti < 4; ti++) {
          int trow = ti * 16 + fr;
          const unsigned short* pb =
              (fq < 2) ? (Ks2 + trow * 128 + (((h * 2 + fq) ^ (trow & 7)) << 3))
                       : (const unsigned short*)&zchunk;
          bf[ti] = *(const f16x8*)pb;
        }
#pragma unroll
        for (int mi = 0; mi < 4; mi++)
#pragma unroll
          for (int ti = 0; ti < 4; ti++)
            sc[mi][ti] = __builtin_amdgcn_mfma_f32_16x16x32_f16(
                af[mi], bf[ti], sc[mi][ti], 0, 0, 0);
      }
#pragma unroll
      for (int mi = 0; mi < 4; mi++) {
#pragma unroll
        for (int r = 0; r < 4; r++) {
          float m = -1e30f;
#pragma unroll
          for (int ti = 0; ti < 4; ti++) m = fmaxf(m, sc[mi][ti][r]);
          m = fmaxf(m, __shfl_xor(m, 1, 64));
          m = fmaxf(m, __shfl_xor(m, 2, 64));
          m = fmaxf(m, __shfl_xor(m, 4, 64));
          m = fmaxf(m, __shfl_xor(m, 8, 64));
          m *= 0.25f;
          float ss = 0.f;
#pragma unroll
          for (int ti = 0; ti < 4; ti++) {
            float p = expf(sc[mi][ti][r] * 0.25f - m);
            sc[mi][ti][r] = p;
            ss += p;
          }
          ss += __shfl_xor(ss, 1, 64);
          ss += __shfl_xor(ss, 2, 64);
          ss += __shfl_xor(ss, 4, 64);
          ss += __shfl_xor(ss, 8, 64);
          float inv = 1.f / ss;
          int prow = mi * 16 + fq * 4 + r;
#pragma unroll
          for (int ti = 0; ti < 4; ti++) {
            int t = ti * 16 + fr;
            Pb[prow * 64 + (((t >> 3) ^ (prow & 7)) << 3) + (t & 7)] =
                f2h(sc[mi][ti][r] * inv);
          }
        }
      }
      // PV
      f32x4 po[4];
#pragma unroll
      for (int i = 0; i < 4; i++) po[i] = (f32x4){0.f, 0.f, 0.f, 0.f};
#pragma unroll
      for (int ks2 = 0; ks2 < 2; ks2++) {
        f16x8 af[4], bf;
#pragma unroll
        for (int si = 0; si < 4; si++) {
          int prow = si * 16 + fr;
          int kq = (ks2 * 4 + fq) ^ (prow & 7);
          af[si] = *(const f16x8*)(Pb + prow * 64 + kq * 8);
        }
        {
          int vrow = h * 16 + fr;
          int kq = (ks2 * 4 + fq) ^ (vrow & 7);
          bf = *(const f16x8*)(VT + vrow * 64 + kq * 8);
        }
#pragma unroll
        for (int si = 0; si < 4; si++)
          po[si] = __builtin_amdgcn_mfma_f32_16x16x32_f16(af[si], bf, po[si],
                                                          0, 0, 0);
      }
#pragma unroll
      for (int si = 0; si < 4; si++)
#pragma unroll
        for (int r = 0; r < 4; r++) {
          int arow = si * 16 + fq * 4 + r;
          int ch = h * 16 + fr;
          AOs[arow * 128 + (((ch >> 3) ^ (arow & 7)) << 3) + (ch & 7)] =
              f2h(po[si][r]);
        }
    }
    __syncthreads();

    // ---- stage Wout ----
#pragma unroll
    for (int i = 0; i < 4; i++) {
      int issue = w * 4 + i;
      int row = issue * 4 + r4;
      int g = cs ^ (row & 7);
      gl2lds16(wout + (size_t)row * 128 + g * 8, (char*)Ws + issue * 1024);
    }
    __syncthreads();

    // ---- phase 4: v = x + ao @ Wout^T + bias ; LN1 -> Xs ----
    {
      f32x4 acc[4];
#pragma unroll
      for (int i = 0; i < 4; i++) acc[i] = (f32x4){0.f, 0.f, 0.f, 0.f};
#pragma unroll
      for (int ks = 0; ks < 4; ks++) {
        f16x8 af[4], bf;
#pragma unroll
        for (int si = 0; si < 4; si++) {
          int row = si * 16 + fr;
          int kq = (ks * 4 + fq) ^ (row & 7);
          af[si] = *(const f16x8*)(AOs + row * 128 + kq * 8);
        }
        {
          int wr = w * 16 + fr;
          int kq = (ks * 4 + fq) ^ (wr & 7);
          bf = *(const f16x8*)(Ws + wr * 128 + kq * 8);
        }
#pragma unroll
        for (int si = 0; si < 4; si++)
          acc[si] = __builtin_amdgcn_mfma_f32_16x16x32_f16(af[si], bf, acc[si],
                                                           0, 0, 0);
      }
      float bv = bout[c];
      float vv4[4][4];
      float sums[4][4], sqs[4][4];
#pragma unroll
      for (int si = 0; si < 4; si++)
#pragma unroll
        for (int r = 0; r < 4; r++) {
          float v = acc[si][r] + bv + xres[si][r];
          vv4[si][r] = v;
          sums[si][r] = v;
          sqs[si][r] = v * v;
        }
#pragma unroll
      for (int d = 1; d < 16; d <<= 1) {
#pragma unroll
        for (int si = 0; si < 4; si++)
#pragma unroll
          for (int r = 0; r < 4; r++) {
            sums[si][r] += __shfl_xor(sums[si][r], d, 64);
            sqs[si][r] += __shfl_xor(sqs[si][r], d, 64);
          }
      }
      if (fr == 0) {
#pragma unroll
        for (int si = 0; si < 4; si++)
#pragma unroll
          for (int r = 0; r < 4; r++) {
            int row = si * 16 + fq * 4 + r;
            psum[w][row] = sums[si][r];
            psq[w][row] = sqs[si][r];
          }
      }
      __syncthreads();  // A: Ws/U1 reusable

      // FFN prologue staging: W1(0)->Ws[0], W2(0)->U1
#pragma unroll
      for (int i = 0; i < 4; i++) {
        int issue = w * 4 + i;
        int row = issue * 4 + r4;
        int g = cs ^ (row & 7);
        gl2lds16(w1 + (size_t)row * 128 + g * 8, (char*)Ws + issue * 1024);
        gl2lds16(w2 + (size_t)row * 2048 + g * 8, (char*)U1 + issue * 1024);
      }
      if (tid < 64) {
        float S = 0.f, Q = 0.f;
#pragma unroll
        for (int ww = 0; ww < 8; ww++) { S += psum[ww][tid]; Q += psq[ww][tid]; }
        float m = S * (1.f / 128.f);
        float var = Q * (1.f / 128.f) - m * m;
        stats[tid] = make_float2(m, rsqrtf(var + 1e-5f));
      }
      __syncthreads();  // B
      float gl = ln1g[c], bl = ln1b[c];
#pragma unroll
      for (int si = 0; si < 4; si++)
#pragma unroll
        for (int r = 0; r < 4; r++) {
          int row = si * 16 + fq * 4 + r;
          float2 st2 = stats[row];
          float y = (vv4[si][r] - st2.x) * st2.y * gl + bl;
          Xs[row * 128 + (((c >> 3) ^ (row & 7)) << 3) + (c & 7)] = f2h(y);
        }
    }
    __syncthreads();  // C: Xs (LN1 out) published; W1(0)/W2(0) drained

    // hoisted FFN x A-fragments
    f16x8 xfragF[4][4];
#pragma unroll
    for (int ks = 0; ks < 4; ks++)
#pragma unroll
      for (int mi = 0; mi < 4; mi++) {
        int row = mi * 16 + fr;
        int kq = (ks * 4 + fq) ^ (row & 7);
        xfragF[ks][mi] = *(const f16x8*)(Xs + row * 128 + kq * 8);
      }

    // ---- FFN chunk loop ----
    f32x4 acc2[4];
#pragma unroll
    for (int i = 0; i < 4; i++) acc2[i] = (f32x4){0.f, 0.f, 0.f, 0.f};

    for (int ch = 0; ch < 16; ch++) {
      const unsigned short* W1cur = Ws + (ch & 1) * 16384;
      f32x4 acc1[4];
#pragma unroll
      for (int i = 0; i < 4; i++) acc1[i] = (f32x4){0.f, 0.f, 0.f, 0.f};
#pragma unroll
      for (int ks = 0; ks < 4; ks++) {
        f16x8 bf;
        {
          int row = w * 16 + fr;
          int kq = (ks * 4 + fq) ^ (row & 7);
          bf = *(const f16x8*)(W1cur + row * 128 + kq * 8);
        }
#pragma unroll
        for (int mi = 0; mi < 4; mi++)
          acc1[mi] = __builtin_amdgcn_mfma_f32_16x16x32_f16(xfragF[ks][mi], bf,
                                                            acc1[mi], 0, 0, 0);
      }
      if (ch < 15) {
#pragma unroll
        for (int i = 0; i < 4; i++) {
          int issue = w * 4 + i;
          int row = issue * 4 + r4;
          int g = cs ^ (row & 7);
          gl2lds16(w1 + (size_t)((ch + 1) * 128 + row) * 128 + g * 8,
                   (char*)Ws + ((ch + 1) & 1) * 32768 + issue * 1024);
        }
      }
      {
        float bv = b1[ch * 128 + c];
#pragma unroll
        for (int mi = 0; mi < 4; mi++)
#pragma unroll
          for (int r = 0; r < 4; r++) {
            int row = mi * 16 + fq * 4 + r;
            Hs[row * 128 + (((c >> 3) ^ (row & 7)) << 3) + (c & 7)] =
                f2h(fmaxf(acc1[mi][r] + bv, 0.f));
          }
      }
      __syncthreads();  // B1

#pragma unroll
      for (int ks = 0; ks < 4; ks++) {
        f16x8 af[4], bf;
#pragma unroll
        for (int si = 0; si < 4; si++) {
          int row = si * 16 + fr;
          int kq = (ks * 4 + fq) ^ (row & 7);
          af[si] = *(const f16x8*)(Hs + row * 128 + kq * 8);
        }
        {
          int row = w * 16 + fr;
          int kq = (ks * 4 + fq) ^ (row & 7);
          bf = *(const f16x8*)(U1 + row * 128 + kq * 8);
        }
#pragma unroll
        for (int si = 0; si < 4; si++)
          acc2[si] = __builtin_amdgcn_mfma_f32_16x16x32_f16(af[si], bf,
                                                            acc2[si], 0, 0, 0);
      }
      __syncthreads();  // B2
      if (ch < 15) {
#pragma unroll
        for (int i = 0; i < 4; i++) {
          int issue = w * 4 + i;
          int row = issue * 4 + r4;
          int g = cs ^ (row & 7);
          gl2lds16(w2 + (size_t)row * 2048 + (ch + 1) * 128 + g * 8,
                   (char*)U1 + issue * 1024);
        }
      }
    }

    // ---- FFN epilogue: +b2 + resid(Xs=LN1 out), LN2 -> xres + Xs ----
    {
      float bv = b2[c];
      float vv4[4][4];
      float sums[4][4], sqs[4][4];
#pragma unroll
      for (int si = 0; si < 4; si++)
#pragma unroll
        for (int r = 0; r < 4; r++) {
          int row = si * 16 + fq * 4 + r;
          float resid =
              h2f(Xs[row * 128 + (((c >> 3) ^ (row & 7)) << 3) + (c & 7)]);
          float v = acc2[si][r] + bv + resid;
          vv4[si][r] = v;
          sums[si][r] = v;
          sqs[si][r] = v * v;
        }
#pragma unroll
      for (int d = 1; d < 16; d <<= 1) {
#pragma unroll
        for (int si = 0; si < 4; si++)
#pragma unroll
          for (int r = 0; r < 4; r++) {
            sums[si][r] += __shfl_xor(sums[si][r], d, 64);
            sqs[si][r] += __shfl_xor(sqs[si][r], d, 64);
          }
      }
      if (fr == 0) {
#pragma unroll
        for (int si = 0; si < 4; si++)
#pragma unroll
          for (int r = 0; r < 4; r++) {
            int row = si * 16 + fq * 4 + r;
            psum[w][row] = sums[si][r];
            psq[w][row] = sqs[si][r];
          }
      }
      __syncthreads();
      if (tid < 64) {
        float S = 0.f, Q = 0.f;
#pragma unroll
        for (int ww = 0; ww < 8; ww++) { S += psum[ww][tid]; Q += psq[ww][tid]; }
        float m = S * (1.f / 128.f);
        float var = Q * (1.f / 128.f) - m * m;
        stats[tid] = make_float2(m, rsqrtf(var + 1e-5f));
      }
      __syncthreads();
      float gl = ln2g[c], bl = ln2b[c];
#pragma unroll
      for (int si = 0; si < 4; si++)
#pragma unroll
        for (int r = 0; r < 4; r++) {
          int row = si * 16 + fq * 4 + r;
          float2 st = stats[row];
          float y = (vv4[si][r] - st.x) * st.y * gl + bl;
          xres[si][r] = y;
          Xs[row * 128 + (((c >> 3) ^ (row & 7)) << 3) + (c & 7)] = f2h(y);
        }
    }
    __syncthreads();  // Xs stable for next layer (or final store)
  }

  // ---- final store: x (f16) -> global for s2s ----
#pragma unroll
  for (int si = 0; si < 4; si++)
#pragma unroll
    for (int r = 0; r < 4; r++) {
      int row = si * 16 + fq * 4 + r;
      xbo[(size_t)(row * 256 + b) * 128 + c] = f2h(xres[si][r]);
    }
}

// ---------------------------------------------------------------------------
// Set2Set (6 steps) + memory LSTM + lin1 + lin3. One 512-thread block per
// segment. (512,1): 256-VGPR cap keeps the 48 uint4 gate weights resident.
// Input xb is f16 now (direct copy into LDS).
// ---------------------------------------------------------------------------
__global__ __launch_bounds__(512, 1) void s2s_kernel(
    const unsigned short* __restrict__ xb,
    const unsigned short* __restrict__ wihh,
    const unsigned short* __restrict__ whhh,
    const float* __restrict__ bih, const float* __restrict__ bhh,
    const unsigned short* __restrict__ mwihh,
    const float* __restrict__ mbih, const float* __restrict__ mbhh,
    const float* __restrict__ l1w, const float* __restrict__ l1b,
    const float* __restrict__ l3w, const float* __restrict__ l3b,
    float* __restrict__ out) {
  __shared__ __align__(16) unsigned xl[256 * 65];
  __shared__ __align__(16) unsigned qu[128];
  __shared__ __align__(16) float cst[128];
  __shared__ __align__(16) float gates[512];
  __shared__ __align__(16) float red[256];
  __shared__ __align__(16) float aw[256];
  int s = blockIdx.x, t = threadIdx.x, lane = t & 63, w = t >> 6;

  uint4 wreg[32], ureg[16];
  {
    const uint4* wp = (const uint4*)(wihh + (size_t)t * 256);
#pragma unroll
    for (int i = 0; i < 32; i++) wreg[i] = wp[i];
    const uint4* up = (const uint4*)(whhh + (size_t)t * 128);
#pragma unroll
    for (int i = 0; i < 16; i++) ureg[i] = up[i];
  }

  const uint4* xs4 = (const uint4*)(xb + (size_t)s * 32768);
#pragma unroll
  for (int it = 0; it < 8; it++) {
    int f = it * 512 + t;
    uint4 v = xs4[f];
    int n = f >> 4, jc = (f & 15) * 4;
    unsigned* dst = xl + n * 65 + jc;
    dst[0] = v.x; dst[1] = v.y; dst[2] = v.z; dst[3] = v.w;
  }
  if (t < 128) cst[t] = 0.f;
  __syncthreads();

  const uint4* q4 = (const uint4*)qu;
  float bsum = bih[t] + bhh[t];

  for (int step = 0; step < 6; step++) {
    if (step > 0) {
      float a0 = 0.f, a1 = 0.f, a2 = 0.f, a3 = 0.f;
#pragma unroll
      for (int i = 0; i < 16; i++) {
        uint4 qv = q4[i];
        a0 = fdot2u(wreg[i].x, qv.x, a0);
        a1 = fdot2u(wreg[i].y, qv.y, a1);
        a2 = fdot2u(wreg[i].z, qv.z, a2);
        a3 = fdot2u(wreg[i].w, qv.w, a3);
        a0 = fdot2u(ureg[i].x, qv.x, a0);
        a1 = fdot2u(ureg[i].y, qv.y, a1);
        a2 = fdot2u(ureg[i].z, qv.z, a2);
        a3 = fdot2u(ureg[i].w, qv.w, a3);
      }
#pragma unroll
      for (int i = 16; i < 32; i++) {
        uint4 qv = q4[i];
        a0 = fdot2u(wreg[i].x, qv.x, a0);
        a1 = fdot2u(wreg[i].y, qv.y, a1);
        a2 = fdot2u(wreg[i].z, qv.z, a2);
        a3 = fdot2u(wreg[i].w, qv.w, a3);
      }
      gates[t] = bsum + ((a0 + a1) + (a2 + a3));
    } else {
      gates[t] = bsum;
    }
    __syncthreads();
    if (t < 128) {
      float ig = sigf(gates[t]), fg = sigf(gates[128 + t]);
      float gg = tanhf(gates[256 + t]), og = sigf(gates[384 + t]);
      float cn = fg * cst[t] + ig * gg;
      cst[t] = cn;
      float hn = og * tanhf(cn);
      float hp = __shfl_xor(hn, 1, 64);
      if ((t & 1) == 0) qu[t >> 1] = packh(hn, hp);
    }
    __syncthreads();
    if (step > 0) {
      int n = t >> 1, p = t & 1;
      const unsigned* xr = xl + n * 65 + p * 32;
      float e0 = 0.f, e1 = 0.f;
#pragma unroll 8
      for (int i = 0; i < 32; i += 2) {
        e0 = fdot2u(xr[i], qu[p * 32 + i], e0);
        e1 = fdot2u(xr[i + 1], qu[p * 32 + i + 1], e1);
      }
      float e = e0 + e1;
      e += __shfl_xor(e, 1, 64);
      if (p == 0) red[n] = e;
      __syncthreads();
      float v0 = red[lane], v1 = red[64 + lane];
      float v2 = red[128 + lane], v3 = red[192 + lane];
      float m = fmaxf(fmaxf(v0, v1), fmaxf(v2, v3));
#pragma unroll
      for (int d = 1; d < 64; d <<= 1) m = fmaxf(m, __shfl_xor(m, d, 64));
      float p0 = expf(v0 - m), p1 = expf(v1 - m);
      float p2 = expf(v2 - m), p3 = expf(v3 - m);
      float ss = p0 + p1 + p2 + p3;
#pragma unroll
      for (int d = 1; d < 64; d <<= 1) ss += __shfl_xor(ss, d, 64);
      float Sinv = 1.f / ss;
      if (w == 0) {
        aw[lane] = p0 * Sinv; aw[64 + lane] = p1 * Sinv;
        aw[128 + lane] = p2 * Sinv; aw[192 + lane] = p3 * Sinv;
      }
    } else {
      if (t < 256) aw[t] = 1.f / 256.f;
    }
    __syncthreads();
    {
      int d = t & 127, grp = t >> 7;
      const unsigned* xc = xl + grp * 64 * 65 + (d >> 1);
      int hi = d & 1;
      const float* ap = aw + grp * 64;
      float r = 0.f;
#pragma unroll 8
      for (int n2 = 0; n2 < 64; n2++) {
        unsigned u = xc[n2 * 65];
        r += ap[n2] * (hi ? hhi(u) : hlo(u));
      }
      gates[t] = r;
    }
    __syncthreads();
    if (t < 128) {
      float rd = gates[t] + gates[128 + t] + gates[256 + t] + gates[384 + t];
      float rp = __shfl_xor(rd, 1, 64);
      if ((t & 1) == 0) qu[64 + (t >> 1)] = packh(rd, rp);
    }
    __syncthreads();
  }
  {
    float a0 = 0.f, a1 = 0.f, a2 = 0.f, a3 = 0.f;
    const uint4* mp = (const uint4*)(mwihh + (size_t)t * 256);
#pragma unroll 8
    for (int i = 0; i < 32; i++) {
      uint4 wv = mp[i], qv = q4[i];
      a0 = fdot2u(wv.x, qv.x, a0);
      a1 = fdot2u(wv.y, qv.y, a1);
      a2 = fdot2u(wv.z, qv.z, a2);
      a3 = fdot2u(wv.w, qv.w, a3);
    }
    gates[t] = mbih[t] + mbhh[t] + ((a0 + a1) + (a2 + a3));
  }
  __syncthreads();
  if (t < 128) {
    float ig = sigf(gates[t]);
    float gg = tanhf(gates[256 + t]);
    float og = sigf(gates[384 + t]);
    float cx = ig * gg;
    float hx = og * tanhf(cx);
    cst[t] = hx;
    out[64 + s * 128 + t] = hx;
    out[64 + 8192 + s * 128 + t] = cx;
  }
  __syncthreads();
  if (t < 128) {
    float acc = l1b[t];
    const float4* w4 = (const float4*)(l1w + (size_t)t * 128);
    const float4* h4 = (const float4*)cst;
#pragma unroll 8
    for (int k = 0; k < 32; k++) {
      float4 a = w4[k], b = h4[k];
      acc += a.x * b.x + a.y * b.y + a.z * b.z + a.w * b.w;
    }
    red[t] = fmaxf(acc, 0.f) * l3w[t];
  } else if (t < 256) {
    red[t] = 0.f;
  }
  __syncthreads();
  for (int off = 128; off; off >>= 1) {
    if (t < off) red[t] += red[t + off];
    __syncthreads();
  }
  if (t == 0) out[s] = red[0] + l3b[0];
}

// ---------------------------------------------------------------------------
extern "C" void kernel_launch(void* const* d_in, const int* in_sizes, int n_in,
                              void* d_out, int out_size, void* d_ws,
                              size_t ws_size, hipStream_t stream) {
  const float* data       = (const float*)d_in[0];
  const float* lin0_w     = (const float*)d_in[1];
  const float* lin0_b     = (const float*)d_in[2];
  const float* attn_in_w  = (const float*)d_in[3];
  const float* attn_in_b  = (const float*)d_in[4];
  const float* attn_out_w = (const float*)d_in[5];
  const float* attn_out_b = (const float*)d_in[6];
  const float* ln1_g      = (const float*)d_in[7];
  const float* ln1_b      = (const float*)d_in[8];
  const float* ff_w1      = (const float*)d_in[9];
  const float* ff_b1      = (const float*)d_in[10];
  const float* ff_w2      = (const float*)d_in[11];
  const float* ff_b2      = (const float*)d_in[12];
  const float* ln2_g      = (const float*)d_in[13];
  const float* ln2_b      = (const float*)d_in[14];
  const float* s2s_wih    = (const float*)d_in[15];
  const float* s2s_whh    = (const float*)d_in[16];
  const float* s2s_bih    = (const float*)d_in[17];
  const float* s2s_bhh    = (const float*)d_in[18];
  const float* mem_wih    = (const float*)d_in[19];
  const float* mem_bih    = (const float*)d_in[21];
  const float* mem_bhh    = (const float*)d_in[22];
  const float* lin1_w     = (const float*)d_in[23];
  const float* lin1_b     = (const float*)d_in[24];
  const float* lin3_w     = (const float*)d_in[25];
  const float* lin3_b     = (const float*)d_in[26];
  float* out = (float*)d_out;

  char* p = (char*)d_ws;
  unsigned short* xb = (unsigned short*)p;   p += (size_t)16384 * 128 * 2;
  unsigned short* wqkv = (unsigned short*)p; p += (size_t)294912 * 2;
  unsigned short* wout = (unsigned short*)p; p += (size_t)98304 * 2;
  unsigned short* w1h = (unsigned short*)p;  p += (size_t)1572864 * 2;
  unsigned short* w2h = (unsigned short*)p;  p += (size_t)1572864 * 2;
  unsigned short* wihh = (unsigned short*)p; p += (size_t)131072 * 2;
  unsigned short* whhh = (unsigned short*)p; p += (size_t)65536 * 2;
  unsigned short* mwihh = (unsigned short*)p; p += (size_t)131072 * 2;

  convw_kernel<<<15104, 256, 0, stream>>>(
      attn_in_w, attn_out_w, ff_w1, ff_w2, s2s_wih, s2s_whh, mem_wih,
      wqkv, wout, w1h, w2h, wihh, whhh, mwihh);

  trans_kernel<<<256, 512, 0, stream>>>(
      data, lin0_w, lin0_b, wqkv, attn_in_b, wout, attn_out_b,
      ln1_g, ln1_b, w1h, ff_b1, w2h, ff_b2, ln2_g, ln2_b, xb);

  s2s_kernel<<<64, 512, 0, stream>>>(
      xb, wihh, whhh, s2s_bih, s2s_bhh,
      mwihh, mem_bih, mem_bhh, lin1_w, lin1_b, lin3_w, lin3_b, out);
}

// Round 11
// 576.553 us; speedup vs baseline: 1.1070x; 1.1070x over previous
//
#include <hip/hip_runtime.h>
#include <math.h>

// S=64 seq, B=256 atoms, N=16384, D=128, H=8, HD=16, DFF=2048, NL=6.
// R11: per-layer dispatches (lockstep preserves cross-block L2 weight reuse —
// R10's mega-kernel lost it, FETCH 11->242MB). All weight B-fragments are
// wave-private (wave w reads only rows w*16+fr) -> loaded DIRECTLY global->
// VGPR: no weight LDS, no staging barriers, reg-loads pipeline across
// s_barrier. ~24 barriers/layer (was ~42). f16 datapath throughout.

typedef _Float16 __attribute__((ext_vector_type(8))) f16x8;
typedef __attribute__((ext_vector_type(4))) float f32x4;
typedef _Float16 __attribute__((ext_vector_type(2))) h16x2;

__device__ __forceinline__ unsigned short f2h(float f) {
  union { _Float16 h; unsigned short s; } x; x.h = (_Float16)f; return x.s;
}
__device__ __forceinline__ float h2f(unsigned short u) {
  union { unsigned short s; _Float16 h; } x; x.s = u; return (float)x.h;
}
__device__ __forceinline__ unsigned packh(float a, float b) {
  return (unsigned)f2h(a) | ((unsigned)f2h(b) << 16);
}
__device__ __forceinline__ float hlo(unsigned u) {
  union { unsigned short s; _Float16 h; } x; x.s = (unsigned short)(u & 0xffff);
  return (float)x.h;
}
__device__ __forceinline__ float hhi(unsigned u) {
  union { unsigned short s; _Float16 h; } x; x.s = (unsigned short)(u >> 16);
  return (float)x.h;
}
__device__ __forceinline__ float fdot2u(unsigned a, unsigned b, float c) {
#if __has_builtin(__builtin_amdgcn_fdot2)
  union U { unsigned u; h16x2 h; };
  U x, y; x.u = a; y.u = b;
  return __builtin_amdgcn_fdot2(x.h, y.h, c, false);
#else
  return c + hlo(a) * hlo(b) + hhi(a) * hhi(b);
#endif
}
__device__ __forceinline__ float sigf(float x) { return 1.f / (1.f + expf(-x)); }

// async 16B global->LDS; LDS base wave-uniform (+ lane*16 implicit).
__device__ __forceinline__ void gl2lds16(const void* g, void* l) {
  __builtin_amdgcn_global_load_lds(
      (const __attribute__((address_space(1))) unsigned int*)g,
      (__attribute__((address_space(3))) unsigned int*)l, 16, 0, 0);
}

// ---------------------------------------------------------------------------
// weight conversion: everything -> f16.
// aiw 294912 | aow 98304 | w1 1572864 | w2 1572864
// | wih 131072 | whh 65536 | mwih 131072   -> total 3866624
// ---------------------------------------------------------------------------
__global__ __launch_bounds__(256) void convw_kernel(
    const float* __restrict__ aiw, const float* __restrict__ aow,
    const float* __restrict__ w1, const float* __restrict__ w2,
    const float* __restrict__ wih, const float* __restrict__ whh,
    const float* __restrict__ mwih,
    unsigned short* __restrict__ o0, unsigned short* __restrict__ o1,
    unsigned short* __restrict__ o2, unsigned short* __restrict__ o3,
    unsigned short* __restrict__ o4, unsigned short* __restrict__ o5,
    unsigned short* __restrict__ o6) {
  int i = blockIdx.x * 256 + threadIdx.x;
  if (i < 294912) {
    o0[i] = f2h(aiw[i]);
  } else if (i < 393216) {
    int j = i - 294912; o1[j] = f2h(aow[j]);
  } else if (i < 1966080) {
    int j = i - 393216; o2[j] = f2h(w1[j]);
  } else if (i < 3538944) {
    int j = i - 1966080; o3[j] = f2h(w2[j]);
  } else if (i < 3670016) {
    int j = i - 3538944; o4[j] = f2h(wih[j]);
  } else if (i < 3735552) {
    int j = i - 3670016; o5[j] = f2h(whh[j]);
  } else {
    int j = i - 3735552; o6[j] = f2h(mwih[j]);
  }
}

// ---------------------------------------------------------------------------
// lin0: x = relu(data @ w^T + b), writes fp32 x and f16 xb
// ---------------------------------------------------------------------------
__global__ __launch_bounds__(256) void lin0_kernel(
    const float* __restrict__ data, const float* __restrict__ w,
    const float* __restrict__ b, float* __restrict__ x,
    unsigned short* __restrict__ xb) {
  int i = blockIdx.x * 256 + threadIdx.x;
  int n = i >> 7, d = i & 127;
  float v = b[d] + data[n * 3 + 0] * w[d * 3 + 0]
                 + data[n * 3 + 1] * w[d * 3 + 1]
                 + data[n * 3 + 2] * w[d * 3 + 2];
  v = fmaxf(v, 0.0f);
  x[i] = v;
  xb[i] = f2h(v);
}

// ---------------------------------------------------------------------------
// Fused transformer LAYER: block = atom b (256 blocks), 512 threads, 8 waves.
// Weights: direct global->VGPR B-fragments (wave-private rows w*16+fr).
// LDS: Xs 16K | Qs 16K | Ks2 16K | VT 16K | AOs 16K | Share 64K (P / Hs[2]).
// ---------------------------------------------------------------------------
__global__ __launch_bounds__(512, 2) void layer_kernel(
    const unsigned short* __restrict__ xbg,
    const unsigned short* __restrict__ wqkv, const float* __restrict__ bqkv,
    const unsigned short* __restrict__ wout, const float* __restrict__ bout,
    const float* __restrict__ ln1g, const float* __restrict__ ln1b,
    const unsigned short* __restrict__ w1, const float* __restrict__ b1,
    const unsigned short* __restrict__ w2, const float* __restrict__ b2,
    const float* __restrict__ ln2g, const float* __restrict__ ln2b,
    float* __restrict__ xio, unsigned short* __restrict__ xbo) {
  __shared__ __align__(16) unsigned short Xs[64 * 128];    // 16 KB
  __shared__ __align__(16) unsigned short Qs[64 * 128];    // 16 KB
  __shared__ __align__(16) unsigned short Ks2[64 * 128];   // 16 KB
  __shared__ __align__(16) unsigned short VT[128 * 64];    // 16 KB
  __shared__ __align__(16) unsigned short AOs[64 * 128];   // 16 KB
  __shared__ __align__(16) unsigned short Share[32768];    // 64 KB: P / Hs[2]
  __shared__ __align__(16) uint4 zchunk;
  __shared__ float psum[8][64], psq[8][64];
  __shared__ float2 stats[64];

  int tid = threadIdx.x, w = tid >> 6, lane = tid & 63;
  int b = blockIdx.x;
  int r4 = lane >> 4, cs = lane & 15;
  int fr = lane & 15, fq = lane >> 4;
  int c = w * 16 + fr;  // this thread's weight-row / column (0..127)

  if (tid == 0) zchunk = make_uint4(0u, 0u, 0u, 0u);

  // ---- stage x tile (f16, 16 KB) ----
#pragma unroll
  for (int i = 0; i < 2; i++) {
    int issue = w * 2 + i;
    int row = issue * 4 + r4;  // s index
    int g = cs ^ (row & 7);
    gl2lds16(xbg + (size_t)(row * 256 + b) * 128 + g * 8,
             (char*)Xs + issue * 1024);
  }
  __syncthreads();  // P0: x visible

  // hoisted x A-fragments (QKV phase)
  f16x8 xfragA[4][4];
#pragma unroll
  for (int ks = 0; ks < 4; ks++)
#pragma unroll
    for (int mi = 0; mi < 4; mi++) {
      int row = mi * 16 + fr;
      int kq = (ks * 4 + fq) ^ (row & 7);
      xfragA[ks][mi] = *(const f16x8*)(Xs + row * 128 + kq * 8);
    }

  // ---- merged phase 1+2: Q,K,V (weights direct from global) ----
  {
    f16x8 bqk[4][2], bv4[4];
#pragma unroll
    for (int ks = 0; ks < 4; ks++) {
#pragma unroll
      for (int ni = 0; ni < 2; ni++) {
        int wr = (w * 2 + ni) * 16 + fr;
        bqk[ks][ni] =
            *(const f16x8*)(wqkv + (size_t)wr * 128 + ks * 32 + fq * 8);
      }
      int vr = 256 + c;
      bv4[ks] = *(const f16x8*)(wqkv + (size_t)vr * 128 + ks * 32 + fq * 8);
    }
    f32x4 aQK[4][2], aV[4];
#pragma unroll
    for (int i = 0; i < 4; i++) {
#pragma unroll
      for (int j = 0; j < 2; j++) aQK[i][j] = (f32x4){0.f, 0.f, 0.f, 0.f};
      aV[i] = (f32x4){0.f, 0.f, 0.f, 0.f};
    }
#pragma unroll
    for (int ks = 0; ks < 4; ks++) {
#pragma unroll
      for (int mi = 0; mi < 4; mi++) {
#pragma unroll
        for (int ni = 0; ni < 2; ni++)
          aQK[mi][ni] = __builtin_amdgcn_mfma_f32_16x16x32_f16(
              xfragA[ks][mi], bqk[ks][ni], aQK[mi][ni], 0, 0, 0);
        aV[mi] = __builtin_amdgcn_mfma_f32_16x16x32_f16(
            xfragA[ks][mi], bv4[ks], aV[mi], 0, 0, 0);
      }
    }
    // write Q/K
#pragma unroll
    for (int ni = 0; ni < 2; ni++) {
      int cq = (w * 2 + ni) * 16 + fr;  // 0..255
      float bv = bqkv[cq];
      unsigned short* dst = (cq < 128) ? Qs : Ks2;
      int cc = cq & 127;
#pragma unroll
      for (int mi = 0; mi < 4; mi++)
#pragma unroll
        for (int r = 0; r < 4; r++) {
          int row = mi * 16 + fq * 4 + r;
          dst[row * 128 + (((cc >> 3) ^ (row & 7)) << 3) + (cc & 7)] =
              f2h(aQK[mi][ni][r] + bv);
        }
    }
    // write V transposed
    float bv = bqkv[256 + c];
#pragma unroll
    for (int mi = 0; mi < 4; mi++)
#pragma unroll
      for (int r = 0; r < 4; r++) {
        int srow = mi * 16 + fq * 4 + r;
        VT[c * 64 + (((srow >> 3) ^ (c & 7)) << 3) + (srow & 7)] =
            f2h(aV[mi][r] + bv);
      }
  }
  __syncthreads();  // P2: Q/K/VT visible

  // ---- phase 3: per-wave head attention (head h = w), P in Share ----
  {
    int h = w;
    unsigned short* Pb = Share + w * 4096;  // 8 KB per wave
    f32x4 sc[4][4];
#pragma unroll
    for (int i = 0; i < 4; i++)
#pragma unroll
      for (int j = 0; j < 4; j++) sc[i][j] = (f32x4){0.f, 0.f, 0.f, 0.f};
    {
      f16x8 af[4], bf[4];
#pragma unroll
      for (int mi = 0; mi < 4; mi++) {
        int row = mi * 16 + fr;
        const unsigned short* pa =
            (fq < 2) ? (Qs + row * 128 + (((h * 2 + fq) ^ (row & 7)) << 3))
                     : (const unsigned short*)&zchunk;
        af[mi] = *(const f16x8*)pa;
      }
#pragma unroll
      for (int ti = 0; ti < 4; ti++) {
        int trow = ti * 16 + fr;
        const unsigned short* pb =
            (fq < 2) ? (Ks2 + trow * 128 + (((h * 2 + fq) ^ (trow & 7)) << 3))
                     : (const unsigned short*)&zchunk;
        bf[ti] = *(const f16x8*)pb;
      }
#pragma unroll
      for (int mi = 0; mi < 4; mi++)
#pragma unroll
        for (int ti = 0; ti < 4; ti++)
          sc[mi][ti] = __builtin_amdgcn_mfma_f32_16x16x32_f16(
              af[mi], bf[ti], sc[mi][ti], 0, 0, 0);
    }
#pragma unroll
    for (int mi = 0; mi < 4; mi++) {
#pragma unroll
      for (int r = 0; r < 4; r++) {
        float m = -1e30f;
#pragma unroll
        for (int ti = 0; ti < 4; ti++) m = fmaxf(m, sc[mi][ti][r]);
        m = fmaxf(m, __shfl_xor(m, 1, 64));
        m = fmaxf(m, __shfl_xor(m, 2, 64));
        m = fmaxf(m, __shfl_xor(m, 4, 64));
        m = fmaxf(m, __shfl_xor(m, 8, 64));
        m *= 0.25f;
        float ss = 0.f;
#pragma unroll
        for (int ti = 0; ti < 4; ti++) {
          float p = expf(sc[mi][ti][r] * 0.25f - m);
          sc[mi][ti][r] = p;
          ss += p;
        }
        ss += __shfl_xor(ss, 1, 64);
        ss += __shfl_xor(ss, 2, 64);
        ss += __shfl_xor(ss, 4, 64);
        ss += __shfl_xor(ss, 8, 64);
        float inv = 1.f / ss;
        int prow = mi * 16 + fq * 4 + r;
#pragma unroll
        for (int ti = 0; ti < 4; ti++) {
          int t = ti * 16 + fr;
          Pb[prow * 64 + (((t >> 3) ^ (prow & 7)) << 3) + (t & 7)] =
              f2h(sc[mi][ti][r] * inv);
        }
      }
    }
    // PV
    f32x4 po[4];
#pragma unroll
    for (int i = 0; i < 4; i++) po[i] = (f32x4){0.f, 0.f, 0.f, 0.f};
#pragma unroll
    for (int ks2 = 0; ks2 < 2; ks2++) {
      f16x8 af[4], bf;
#pragma unroll
      for (int si = 0; si < 4; si++) {
        int prow = si * 16 + fr;
        int kq = (ks2 * 4 + fq) ^ (prow & 7);
        af[si] = *(const f16x8*)(Pb + prow * 64 + kq * 8);
      }
      {
        int vrow = h * 16 + fr;
        int kq = (ks2 * 4 + fq) ^ (vrow & 7);
        bf = *(const f16x8*)(VT + vrow * 64 + kq * 8);
      }
#pragma unroll
      for (int si = 0; si < 4; si++)
        po[si] = __builtin_amdgcn_mfma_f32_16x16x32_f16(af[si], bf, po[si],
                                                        0, 0, 0);
    }
#pragma unroll
    for (int si = 0; si < 4; si++)
#pragma unroll
      for (int r = 0; r < 4; r++) {
        int arow = si * 16 + fq * 4 + r;
        int ch = h * 16 + fr;
        AOs[arow * 128 + (((ch >> 3) ^ (arow & 7)) << 3) + (ch & 7)] =
            f2h(po[si][r]);
      }
  }
  __syncthreads();  // P3: AOs visible

  // ---- phase 4: v = x + ao @ Wout^T + bias ; LN1 -> Xs ----
  f16x8 w1f[4], w2f[4];  // FFN chunk-0 weights (prefetched below)
  {
    f16x8 bwo[4];
#pragma unroll
    for (int ks = 0; ks < 4; ks++)
      bwo[ks] = *(const f16x8*)(wout + (size_t)c * 128 + ks * 32 + fq * 8);
    f32x4 acc[4];
#pragma unroll
    for (int i = 0; i < 4; i++) acc[i] = (f32x4){0.f, 0.f, 0.f, 0.f};
#pragma unroll
    for (int ks = 0; ks < 4; ks++) {
      f16x8 af[4];
#pragma unroll
      for (int si = 0; si < 4; si++) {
        int row = si * 16 + fr;
        int kq = (ks * 4 + fq) ^ (row & 7);
        af[si] = *(const f16x8*)(AOs + row * 128 + kq * 8);
      }
#pragma unroll
      for (int si = 0; si < 4; si++)
        acc[si] = __builtin_amdgcn_mfma_f32_16x16x32_f16(af[si], bwo[ks],
                                                         acc[si], 0, 0, 0);
    }
    float bv = bout[c];
    float vv4[4][4];
    float sums[4][4], sqs[4][4];
#pragma unroll
    for (int si = 0; si < 4; si++)
#pragma unroll
      for (int r = 0; r < 4; r++) {
        int row = si * 16 + fq * 4 + r;
        float v = acc[si][r] + bv + xio[(size_t)(row * 256 + b) * 128 + c];
        vv4[si][r] = v;
        sums[si][r] = v;
        sqs[si][r] = v * v;
      }
#pragma unroll
    for (int d = 1; d < 16; d <<= 1) {
#pragma unroll
      for (int si = 0; si < 4; si++)
#pragma unroll
        for (int r = 0; r < 4; r++) {
          sums[si][r] += __shfl_xor(sums[si][r], d, 64);
          sqs[si][r] += __shfl_xor(sqs[si][r], d, 64);
        }
    }
    if (fr == 0) {
#pragma unroll
      for (int si = 0; si < 4; si++)
#pragma unroll
        for (int r = 0; r < 4; r++) {
          int row = si * 16 + fq * 4 + r;
          psum[w][row] = sums[si][r];
          psq[w][row] = sqs[si][r];
        }
    }
    // prefetch FFN chunk-0 weights (reg loads pipeline across barriers)
#pragma unroll
    for (int ks = 0; ks < 4; ks++) {
      w1f[ks] = *(const f16x8*)(w1 + (size_t)c * 128 + ks * 32 + fq * 8);
      w2f[ks] = *(const f16x8*)(w2 + (size_t)c * 2048 + ks * 32 + fq * 8);
    }
    __syncthreads();  // P4: psum visible
    if (tid < 64) {
      float S = 0.f, Q = 0.f;
#pragma unroll
      for (int ww = 0; ww < 8; ww++) { S += psum[ww][tid]; Q += psq[ww][tid]; }
      float m = S * (1.f / 128.f);
      float var = Q * (1.f / 128.f) - m * m;
      stats[tid] = make_float2(m, rsqrtf(var + 1e-5f));
    }
    __syncthreads();  // P5: stats visible
    float gl = ln1g[c], bl = ln1b[c];
#pragma unroll
    for (int si = 0; si < 4; si++)
#pragma unroll
      for (int r = 0; r < 4; r++) {
        int row = si * 16 + fq * 4 + r;
        float2 st2 = stats[row];
        float y = (vv4[si][r] - st2.x) * st2.y * gl + bl;
        Xs[row * 128 + (((c >> 3) ^ (row & 7)) << 3) + (c & 7)] = f2h(y);
      }
  }
  __syncthreads();  // P6: Xs (LN1 out) visible; Share (P) free

  // hoisted FFN x A-fragments
  f16x8 xfragF[4][4];
#pragma unroll
  for (int ks = 0; ks < 4; ks++)
#pragma unroll
    for (int mi = 0; mi < 4; mi++) {
      int row = mi * 16 + fr;
      int kq = (ks * 4 + fq) ^ (row & 7);
      xfragF[ks][mi] = *(const f16x8*)(Xs + row * 128 + kq * 8);
    }

  // ---- FFN: 16 chunks, 1 barrier each; Hs double-buffered in Share ----
  f32x4 acc2[4];
#pragma unroll
  for (int i = 0; i < 4; i++) acc2[i] = (f32x4){0.f, 0.f, 0.f, 0.f};

  for (int ch = 0; ch < 16; ch++) {
    // ff1: wave w -> hidden cols [w*16, w*16+16)
    f32x4 acc1[4];
#pragma unroll
    for (int i = 0; i < 4; i++) acc1[i] = (f32x4){0.f, 0.f, 0.f, 0.f};
#pragma unroll
    for (int ks = 0; ks < 4; ks++)
#pragma unroll
      for (int mi = 0; mi < 4; mi++)
        acc1[mi] = __builtin_amdgcn_mfma_f32_16x16x32_f16(
            xfragF[ks][mi], w1f[ks], acc1[mi], 0, 0, 0);
    // prefetch W1(ch+1) into regs
    if (ch < 15) {
#pragma unroll
      for (int ks = 0; ks < 4; ks++)
        w1f[ks] = *(const f16x8*)(w1 + (size_t)((ch + 1) * 128 + c) * 128 +
                                  ks * 32 + fq * 8);
    }
    // bias + relu -> Hs[ch&1]
    {
      unsigned short* Hc = Share + (ch & 1) * 8192;
      float bv = b1[ch * 128 + c];
#pragma unroll
      for (int mi = 0; mi < 4; mi++)
#pragma unroll
        for (int r = 0; r < 4; r++) {
          int row = mi * 16 + fq * 4 + r;
          Hc[row * 128 + (((c >> 3) ^ (row & 7)) << 3) + (c & 7)] =
              f2h(fmaxf(acc1[mi][r] + bv, 0.f));
        }
    }
    __syncthreads();  // Hs[ch&1] visible

    // ff2: wave w -> out cols [w*16, w*16+16)
    {
      const unsigned short* Hr = Share + (ch & 1) * 8192;
#pragma unroll
      for (int ks = 0; ks < 4; ks++) {
        f16x8 af[4];
#pragma unroll
        for (int si = 0; si < 4; si++) {
          int row = si * 16 + fr;
          int kq = (ks * 4 + fq) ^ (row & 7);
          af[si] = *(const f16x8*)(Hr + row * 128 + kq * 8);
        }
#pragma unroll
        for (int si = 0; si < 4; si++)
          acc2[si] = __builtin_amdgcn_mfma_f32_16x16x32_f16(af[si], w2f[ks],
                                                            acc2[si], 0, 0, 0);
      }
    }
    // prefetch W2(ch+1) into regs
    if (ch < 15) {
#pragma unroll
      for (int ks = 0; ks < 4; ks++)
        w2f[ks] = *(const f16x8*)(w2 + (size_t)c * 2048 + (ch + 1) * 128 +
                                  ks * 32 + fq * 8);
    }
  }

  // ---- FFN epilogue: +b2 + resid(Xs=LN1 out), LN2 -> xio + xbo ----
  {
    float bv = b2[c];
    float vv4[4][4];
    float sums[4][4], sqs[4][4];
#pragma unroll
    for (int si = 0; si < 4; si++)
#pragma unroll
      for (int r = 0; r < 4; r++) {
        int row = si * 16 + fq * 4 + r;
        float resid =
            h2f(Xs[row * 128 + (((c >> 3) ^ (row & 7)) << 3) + (c & 7)]);
        float v = acc2[si][r] + bv + resid;
        vv4[si][r] = v;
        sums[si][r] = v;
        sqs[si][r] = v * v;
      }
#pragma unroll
    for (int d = 1; d < 16; d <<= 1) {
#pragma unroll
      for (int si = 0; si < 4; si++)
#pragma unroll
        for (int r = 0; r < 4; r++) {
          sums[si][r] += __shfl_xor(sums[si][r], d, 64);
          sqs[si][r] += __shfl_xor(sqs[si][r], d, 64);
        }
    }
    if (fr == 0) {
#pragma unroll
      for (int si = 0; si < 4; si++)
#pragma unroll
        for (int r = 0; r < 4; r++) {
          int row = si * 16 + fq * 4 + r;
          psum[w][row] = sums[si][r];
          psq[w][row] = sqs[si][r];
        }
    }
    __syncthreads();
    if (tid < 64) {
      float S = 0.f, Q = 0.f;
#pragma unroll
      for (int ww = 0; ww < 8; ww++) { S += psum[ww][tid]; Q += psq[ww][tid]; }
      float m = S * (1.f / 128.f);
      float var = Q * (1.f / 128.f) - m * m;
      stats[tid] = make_float2(m, rsqrtf(var + 1e-5f));
    }
    __syncthreads();
    float gl = ln2g[c], bl = ln2b[c];
#pragma unroll
    for (int si = 0; si < 4; si++)
#pragma unroll
      for (int r = 0; r < 4; r++) {
        int row = si * 16 + fq * 4 + r;
        float2 st = stats[row];
        float y = (vv4[si][r] - st.x) * st.y * gl + bl;
        size_t o = (size_t)(row * 256 + b) * 128 + c;
        xio[o] = y;
        xbo[o] = f2h(y);
      }
  }
}

// ---------------------------------------------------------------------------
// Set2Set (6 steps) + memory LSTM + lin1 + lin3. One 512-thread block per
// segment. (512,1): 256-VGPR cap keeps the 48 uint4 gate weights resident.
// Input xb is f16 (direct copy into LDS).
// ---------------------------------------------------------------------------
__global__ __launch_bounds__(512, 1) void s2s_kernel(
    const unsigned short* __restrict__ xb,
    const unsigned short* __restrict__ wihh,
    const unsigned short* __restrict__ whhh,
    const float* __restrict__ bih, const float* __restrict__ bhh,
    const unsigned short* __restrict__ mwihh,
    const float* __restrict__ mbih, const float* __restrict__ mbhh,
    const float* __restrict__ l1w, const float* __restrict__ l1b,
    const float* __restrict__ l3w, const float* __restrict__ l3b,
    float* __restrict__ out) {
  __shared__ __align__(16) unsigned xl[256 * 65];
  __shared__ __align__(16) unsigned qu[128];
  __shared__ __align__(16) float cst[128];
  __shared__ __align__(16) float gates[512];
  __shared__ __align__(16) float red[256];
  __shared__ __align__(16) float aw[256];
  int s = blockIdx.x, t = threadIdx.x, lane = t & 63, w = t >> 6;

  uint4 wreg[32], ureg[16];
  {
    const uint4* wp = (const uint4*)(wihh + (size_t)t * 256);
#pragma unroll
    for (int i = 0; i < 32; i++) wreg[i] = wp[i];
    const uint4* up = (const uint4*)(whhh + (size_t)t * 128);
#pragma unroll
    for (int i = 0; i < 16; i++) ureg[i] = up[i];
  }

  const uint4* xs4 = (const uint4*)(xb + (size_t)s * 32768);
#pragma unroll
  for (int it = 0; it < 8; it++) {
    int f = it * 512 + t;
    uint4 v = xs4[f];
    int n = f >> 4, jc = (f & 15) * 4;
    unsigned* dst = xl + n * 65 + jc;
    dst[0] = v.x; dst[1] = v.y; dst[2] = v.z; dst[3] = v.w;
  }
  if (t < 128) cst[t] = 0.f;
  __syncthreads();

  const uint4* q4 = (const uint4*)qu;
  float bsum = bih[t] + bhh[t];

  for (int step = 0; step < 6; step++) {
    if (step > 0) {
      float a0 = 0.f, a1 = 0.f, a2 = 0.f, a3 = 0.f;
#pragma unroll
      for (int i = 0; i < 16; i++) {
        uint4 qv = q4[i];
        a0 = fdot2u(wreg[i].x, qv.x, a0);
        a1 = fdot2u(wreg[i].y, qv.y, a1);
        a2 = fdot2u(wreg[i].z, qv.z, a2);
        a3 = fdot2u(wreg[i].w, qv.w, a3);
        a0 = fdot2u(ureg[i].x, qv.x, a0);
        a1 = fdot2u(ureg[i].y, qv.y, a1);
        a2 = fdot2u(ureg[i].z, qv.z, a2);
        a3 = fdot2u(ureg[i].w, qv.w, a3);
      }
#pragma unroll
      for (int i = 16; i < 32; i++) {
        uint4 qv = q4[i];
        a0 = fdot2u(wreg[i].x, qv.x, a0);
        a1 = fdot2u(wreg[i].y, qv.y, a1);
        a2 = fdot2u(wreg[i].z, qv.z, a2);
        a3 = fdot2u(wreg[i].w, qv.w, a3);
      }
      gates[t] = bsum + ((a0 + a1) + (a2 + a3));
    } else {
      gates[t] = bsum;
    }
    __syncthreads();
    if (t < 128) {
      float ig = sigf(gates[t]), fg = sigf(gates[128 + t]);
      float gg = tanhf(gates[256 + t]), og = sigf(gates[384 + t]);
      float cn = fg * cst[t] + ig * gg;
      cst[t] = cn;
      float hn = og * tanhf(cn);
      float hp = __shfl_xor(hn, 1, 64);
      if ((t & 1) == 0) qu[t >> 1] = packh(hn, hp);
    }
    __syncthreads();
    if (step > 0) {
      int n = t >> 1, p = t & 1;
      const unsigned* xr = xl + n * 65 + p * 32;
      float e0 = 0.f, e1 = 0.f;
#pragma unroll 8
      for (int i = 0; i < 32; i += 2) {
        e0 = fdot2u(xr[i], qu[p * 32 + i], e0);
        e1 = fdot2u(xr[i + 1], qu[p * 32 + i + 1], e1);
      }
      float e = e0 + e1;
      e += __shfl_xor(e, 1, 64);
      if (p == 0) red[n] = e;
      __syncthreads();
      float v0 = red[lane], v1 = red[64 + lane];
      float v2 = red[128 + lane], v3 = red[192 + lane];
      float m = fmaxf(fmaxf(v0, v1), fmaxf(v2, v3));
#pragma unroll
      for (int d = 1; d < 64; d <<= 1) m = fmaxf(m, __shfl_xor(m, d, 64));
      float p0 = expf(v0 - m), p1 = expf(v1 - m);
      float p2 = expf(v2 - m), p3 = expf(v3 - m);
      float ss = p0 + p1 + p2 + p3;
#pragma unroll
      for (int d = 1; d < 64; d <<= 1) ss += __shfl_xor(ss, d, 64);
      float Sinv = 1.f / ss;
      if (w == 0) {
        aw[lane] = p0 * Sinv; aw[64 + lane] = p1 * Sinv;
        aw[128 + lane] = p2 * Sinv; aw[192 + lane] = p3 * Sinv;
      }
    } else {
      if (t < 256) aw[t] = 1.f / 256.f;
    }
    __syncthreads();
    {
      int d = t & 127, grp = t >> 7;
      const unsigned* xc = xl + grp * 64 * 65 + (d >> 1);
      int hi = d & 1;
      const float* ap = aw + grp * 64;
      float r = 0.f;
#pragma unroll 8
      for (int n2 = 0; n2 < 64; n2++) {
        unsigned u = xc[n2 * 65];
        r += ap[n2] * (hi ? hhi(u) : hlo(u));
      }
      gates[t] = r;
    }
    __syncthreads();
    if (t < 128) {
      float rd = gates[t] + gates[128 + t] + gates[256 + t] + gates[384 + t];
      float rp = __shfl_xor(rd, 1, 64);
      if ((t & 1) == 0) qu[64 + (t >> 1)] = packh(rd, rp);
    }
    __syncthreads();
  }
  {
    float a0 = 0.f, a1 = 0.f, a2 = 0.f, a3 = 0.f;
    const uint4* mp = (const uint4*)(mwihh + (size_t)t * 256);
#pragma unroll 8
    for (int i = 0; i < 32; i++) {
      uint4 wv = mp[i], qv = q4[i];
      a0 = fdot2u(wv.x, qv.x, a0);
      a1 = fdot2u(wv.y, qv.y, a1);
      a2 = fdot2u(wv.z, qv.z, a2);
      a3 = fdot2u(wv.w, qv.w, a3);
    }
    gates[t] = mbih[t] + mbhh[t] + ((a0 + a1) + (a2 + a3));
  }
  __syncthreads();
  if (t < 128) {
    float ig = sigf(gates[t]);
    float gg = tanhf(gates[256 + t]);
    float og = sigf(gates[384 + t]);
    float cx = ig * gg;
    float hx = og * tanhf(cx);
    cst[t] = hx;
    out[64 + s * 128 + t] = hx;
    out[64 + 8192 + s * 128 + t] = cx;
  }
  __syncthreads();
  if (t < 128) {
    float acc = l1b[t];
    const float4* w4 = (const float4*)(l1w + (size_t)t * 128);
    const float4* h4 = (const float4*)cst;
#pragma unroll 8
    for (int k = 0; k < 32; k++) {
      float4 a = w4[k], b = h4[k];
      acc += a.x * b.x + a.y * b.y + a.z * b.z + a.w * b.w;
    }
    red[t] = fmaxf(acc, 0.f) * l3w[t];
  } else if (t < 256) {
    red[t] = 0.f;
  }
  __syncthreads();
  for (int off = 128; off; off >>= 1) {
    if (t < off) red[t] += red[t + off];
    __syncthreads();
  }
  if (t == 0) out[s] = red[0] + l3b[0];
}

// ---------------------------------------------------------------------------
extern "C" void kernel_launch(void* const* d_in, const int* in_sizes, int n_in,
                              void* d_out, int out_size, void* d_ws,
                              size_t ws_size, hipStream_t stream) {
  const float* data       = (const float*)d_in[0];
  const float* lin0_w     = (const float*)d_in[1];
  const float* lin0_b     = (const float*)d_in[2];
  const float* attn_in_w  = (const float*)d_in[3];
  const float* attn_in_b  = (const float*)d_in[4];
  const float* attn_out_w = (const float*)d_in[5];
  const float* attn_out_b = (const float*)d_in[6];
  const float* ln1_g      = (const float*)d_in[7];
  const float* ln1_b      = (const float*)d_in[8];
  const float* ff_w1      = (const float*)d_in[9];
  const float* ff_b1      = (const float*)d_in[10];
  const float* ff_w2      = (const float*)d_in[11];
  const float* ff_b2      = (const float*)d_in[12];
  const float* ln2_g      = (const float*)d_in[13];
  const float* ln2_b      = (const float*)d_in[14];
  const float* s2s_wih    = (const float*)d_in[15];
  const float* s2s_whh    = (const float*)d_in[16];
  const float* s2s_bih    = (const float*)d_in[17];
  const float* s2s_bhh    = (const float*)d_in[18];
  const float* mem_wih    = (const float*)d_in[19];
  const float* mem_bih    = (const float*)d_in[21];
  const float* mem_bhh    = (const float*)d_in[22];
  const float* lin1_w     = (const float*)d_in[23];
  const float* lin1_b     = (const float*)d_in[24];
  const float* lin3_w     = (const float*)d_in[25];
  const float* lin3_b     = (const float*)d_in[26];
  float* out = (float*)d_out;

  char* p = (char*)d_ws;
  float* x = (float*)p;                      p += (size_t)16384 * 128 * 4;
  unsigned short* xb = (unsigned short*)p;   p += (size_t)16384 * 128 * 2;
  unsigned short* wqkv = (unsigned short*)p; p += (size_t)294912 * 2;
  unsigned short* wout = (unsigned short*)p; p += (size_t)98304 * 2;
  unsigned short* w1h = (unsigned short*)p;  p += (size_t)1572864 * 2;
  unsigned short* w2h = (unsigned short*)p;  p += (size_t)1572864 * 2;
  unsigned short* wihh = (unsigned short*)p; p += (size_t)131072 * 2;
  unsigned short* whhh = (unsigned short*)p; p += (size_t)65536 * 2;
  unsigned short* mwihh = (unsigned short*)p; p += (size_t)131072 * 2;

  convw_kernel<<<15104, 256, 0, stream>>>(
      attn_in_w, attn_out_w, ff_w1, ff_w2, s2s_wih, s2s_whh, mem_wih,
      wqkv, wout, w1h, w2h, wihh, whhh, mwihh);
  lin0_kernel<<<8192, 256, 0, stream>>>(data, lin0_w, lin0_b, x, xb);

  for (int l = 0; l < 6; l++) {
    layer_kernel<<<256, 512, 0, stream>>>(
        xb, wqkv + (size_t)l * 49152, attn_in_b + l * 384,
        wout + (size_t)l * 16384, attn_out_b + l * 128,
        ln1_g + l * 128, ln1_b + l * 128,
        w1h + (size_t)l * 262144, ff_b1 + l * 2048,
        w2h + (size_t)l * 262144, ff_b2 + l * 128,
        ln2_g + l * 128, ln2_b + l * 128, x, xb);
  }

  s2s_kernel<<<64, 512, 0, stream>>>(
      xb, wihh, whhh, s2s_bih, s2s_bhh,
      mwihh, mem_bih, mem_bhh, lin1_w, lin1_b, lin3_w, lin3_b, out);
}

// Round 12
// 576.066 us; speedup vs baseline: 1.1079x; 1.0008x over previous
//
#include <hip/hip_runtime.h>
#include <math.h>

// S=64 seq, B=256 atoms, N=16384, D=128, H=8, HD=16, DFF=2048, NL=6.
// R12 = R11 with __launch_bounds__(512,1) on layer_kernel: R11's (512,2)
// capped VGPRs at 128 -> massive scratch spills (WRITE_SIZE +9MB/layer).
// 152KB LDS means 1 block/CU regardless, so the 256-VGPR budget is free.
// Weights load直接 global->VGPR (wave-private rows); f16 datapath.

typedef _Float16 __attribute__((ext_vector_type(8))) f16x8;
typedef __attribute__((ext_vector_type(4))) float f32x4;
typedef _Float16 __attribute__((ext_vector_type(2))) h16x2;

__device__ __forceinline__ unsigned short f2h(float f) {
  union { _Float16 h; unsigned short s; } x; x.h = (_Float16)f; return x.s;
}
__device__ __forceinline__ float h2f(unsigned short u) {
  union { unsigned short s; _Float16 h; } x; x.s = u; return (float)x.h;
}
__device__ __forceinline__ unsigned packh(float a, float b) {
  return (unsigned)f2h(a) | ((unsigned)f2h(b) << 16);
}
__device__ __forceinline__ float hlo(unsigned u) {
  union { unsigned short s; _Float16 h; } x; x.s = (unsigned short)(u & 0xffff);
  return (float)x.h;
}
__device__ __forceinline__ float hhi(unsigned u) {
  union { unsigned short s; _Float16 h; } x; x.s = (unsigned short)(u >> 16);
  return (float)x.h;
}
__device__ __forceinline__ float fdot2u(unsigned a, unsigned b, float c) {
#if __has_builtin(__builtin_amdgcn_fdot2)
  union U { unsigned u; h16x2 h; };
  U x, y; x.u = a; y.u = b;
  return __builtin_amdgcn_fdot2(x.h, y.h, c, false);
#else
  return c + hlo(a) * hlo(b) + hhi(a) * hhi(b);
#endif
}
__device__ __forceinline__ float sigf(float x) { return 1.f / (1.f + expf(-x)); }

// async 16B global->LDS; LDS base wave-uniform (+ lane*16 implicit).
__device__ __forceinline__ void gl2lds16(const void* g, void* l) {
  __builtin_amdgcn_global_load_lds(
      (const __attribute__((address_space(1))) unsigned int*)g,
      (__attribute__((address_space(3))) unsigned int*)l, 16, 0, 0);
}

// ---------------------------------------------------------------------------
// weight conversion: everything -> f16.
// aiw 294912 | aow 98304 | w1 1572864 | w2 1572864
// | wih 131072 | whh 65536 | mwih 131072   -> total 3866624
// ---------------------------------------------------------------------------
__global__ __launch_bounds__(256) void convw_kernel(
    const float* __restrict__ aiw, const float* __restrict__ aow,
    const float* __restrict__ w1, const float* __restrict__ w2,
    const float* __restrict__ wih, const float* __restrict__ whh,
    const float* __restrict__ mwih,
    unsigned short* __restrict__ o0, unsigned short* __restrict__ o1,
    unsigned short* __restrict__ o2, unsigned short* __restrict__ o3,
    unsigned short* __restrict__ o4, unsigned short* __restrict__ o5,
    unsigned short* __restrict__ o6) {
  int i = blockIdx.x * 256 + threadIdx.x;
  if (i < 294912) {
    o0[i] = f2h(aiw[i]);
  } else if (i < 393216) {
    int j = i - 294912; o1[j] = f2h(aow[j]);
  } else if (i < 1966080) {
    int j = i - 393216; o2[j] = f2h(w1[j]);
  } else if (i < 3538944) {
    int j = i - 1966080; o3[j] = f2h(w2[j]);
  } else if (i < 3670016) {
    int j = i - 3538944; o4[j] = f2h(wih[j]);
  } else if (i < 3735552) {
    int j = i - 3670016; o5[j] = f2h(whh[j]);
  } else {
    int j = i - 3735552; o6[j] = f2h(mwih[j]);
  }
}

// ---------------------------------------------------------------------------
// lin0: x = relu(data @ w^T + b), writes fp32 x and f16 xb
// ---------------------------------------------------------------------------
__global__ __launch_bounds__(256) void lin0_kernel(
    const float* __restrict__ data, const float* __restrict__ w,
    const float* __restrict__ b, float* __restrict__ x,
    unsigned short* __restrict__ xb) {
  int i = blockIdx.x * 256 + threadIdx.x;
  int n = i >> 7, d = i & 127;
  float v = b[d] + data[n * 3 + 0] * w[d * 3 + 0]
                 + data[n * 3 + 1] * w[d * 3 + 1]
                 + data[n * 3 + 2] * w[d * 3 + 2];
  v = fmaxf(v, 0.0f);
  x[i] = v;
  xb[i] = f2h(v);
}

// ---------------------------------------------------------------------------
// Fused transformer LAYER: block = atom b (256 blocks), 512 threads, 8 waves.
// Weights: direct global->VGPR B-fragments (wave-private rows w*16+fr).
// LDS: Xs 16K | Qs 16K | Ks2 16K | VT 16K | AOs 16K | Share 64K (P / Hs[2]).
// ---------------------------------------------------------------------------
__global__ __launch_bounds__(512, 1) void layer_kernel(
    const unsigned short* __restrict__ xbg,
    const unsigned short* __restrict__ wqkv, const float* __restrict__ bqkv,
    const unsigned short* __restrict__ wout, const float* __restrict__ bout,
    const float* __restrict__ ln1g, const float* __restrict__ ln1b,
    const unsigned short* __restrict__ w1, const float* __restrict__ b1,
    const unsigned short* __restrict__ w2, const float* __restrict__ b2,
    const float* __restrict__ ln2g, const float* __restrict__ ln2b,
    float* __restrict__ xio, unsigned short* __restrict__ xbo) {
  __shared__ __align__(16) unsigned short Xs[64 * 128];    // 16 KB
  __shared__ __align__(16) unsigned short Qs[64 * 128];    // 16 KB
  __shared__ __align__(16) unsigned short Ks2[64 * 128];   // 16 KB
  __shared__ __align__(16) unsigned short VT[128 * 64];    // 16 KB
  __shared__ __align__(16) unsigned short AOs[64 * 128];   // 16 KB
  __shared__ __align__(16) unsigned short Share[32768];    // 64 KB: P / Hs[2]
  __shared__ __align__(16) uint4 zchunk;
  __shared__ float psum[8][64], psq[8][64];
  __shared__ float2 stats[64];

  int tid = threadIdx.x, w = tid >> 6, lane = tid & 63;
  int b = blockIdx.x;
  int r4 = lane >> 4, cs = lane & 15;
  int fr = lane & 15, fq = lane >> 4;
  int c = w * 16 + fr;  // this thread's weight-row / column (0..127)

  if (tid == 0) zchunk = make_uint4(0u, 0u, 0u, 0u);

  // ---- stage x tile (f16, 16 KB) ----
#pragma unroll
  for (int i = 0; i < 2; i++) {
    int issue = w * 2 + i;
    int row = issue * 4 + r4;  // s index
    int g = cs ^ (row & 7);
    gl2lds16(xbg + (size_t)(row * 256 + b) * 128 + g * 8,
             (char*)Xs + issue * 1024);
  }
  __syncthreads();  // P0: x visible

  // hoisted x A-fragments (QKV phase)
  f16x8 xfragA[4][4];
#pragma unroll
  for (int ks = 0; ks < 4; ks++)
#pragma unroll
    for (int mi = 0; mi < 4; mi++) {
      int row = mi * 16 + fr;
      int kq = (ks * 4 + fq) ^ (row & 7);
      xfragA[ks][mi] = *(const f16x8*)(Xs + row * 128 + kq * 8);
    }

  // ---- merged phase 1+2: Q,K,V (weights direct from global) ----
  {
    f16x8 bqk[4][2], bv4[4];
#pragma unroll
    for (int ks = 0; ks < 4; ks++) {
#pragma unroll
      for (int ni = 0; ni < 2; ni++) {
        int wr = (w * 2 + ni) * 16 + fr;
        bqk[ks][ni] =
            *(const f16x8*)(wqkv + (size_t)wr * 128 + ks * 32 + fq * 8);
      }
      int vr = 256 + c;
      bv4[ks] = *(const f16x8*)(wqkv + (size_t)vr * 128 + ks * 32 + fq * 8);
    }
    f32x4 aQK[4][2], aV[4];
#pragma unroll
    for (int i = 0; i < 4; i++) {
#pragma unroll
      for (int j = 0; j < 2; j++) aQK[i][j] = (f32x4){0.f, 0.f, 0.f, 0.f};
      aV[i] = (f32x4){0.f, 0.f, 0.f, 0.f};
    }
#pragma unroll
    for (int ks = 0; ks < 4; ks++) {
#pragma unroll
      for (int mi = 0; mi < 4; mi++) {
#pragma unroll
        for (int ni = 0; ni < 2; ni++)
          aQK[mi][ni] = __builtin_amdgcn_mfma_f32_16x16x32_f16(
              xfragA[ks][mi], bqk[ks][ni], aQK[mi][ni], 0, 0, 0);
        aV[mi] = __builtin_amdgcn_mfma_f32_16x16x32_f16(
            xfragA[ks][mi], bv4[ks], aV[mi], 0, 0, 0);
      }
    }
    // write Q/K
#pragma unroll
    for (int ni = 0; ni < 2; ni++) {
      int cq = (w * 2 + ni) * 16 + fr;  // 0..255
      float bv = bqkv[cq];
      unsigned short* dst = (cq < 128) ? Qs : Ks2;
      int cc = cq & 127;
#pragma unroll
      for (int mi = 0; mi < 4; mi++)
#pragma unroll
        for (int r = 0; r < 4; r++) {
          int row = mi * 16 + fq * 4 + r;
          dst[row * 128 + (((cc >> 3) ^ (row & 7)) << 3) + (cc & 7)] =
              f2h(aQK[mi][ni][r] + bv);
        }
    }
    // write V transposed
    float bv = bqkv[256 + c];
#pragma unroll
    for (int mi = 0; mi < 4; mi++)
#pragma unroll
      for (int r = 0; r < 4; r++) {
        int srow = mi * 16 + fq * 4 + r;
        VT[c * 64 + (((srow >> 3) ^ (c & 7)) << 3) + (srow & 7)] =
            f2h(aV[mi][r] + bv);
      }
  }
  __syncthreads();  // P2: Q/K/VT visible

  // ---- phase 3: per-wave head attention (head h = w), P in Share ----
  {
    int h = w;
    unsigned short* Pb = Share + w * 4096;  // 8 KB per wave
    f32x4 sc[4][4];
#pragma unroll
    for (int i = 0; i < 4; i++)
#pragma unroll
      for (int j = 0; j < 4; j++) sc[i][j] = (f32x4){0.f, 0.f, 0.f, 0.f};
    {
      f16x8 af[4], bf[4];
#pragma unroll
      for (int mi = 0; mi < 4; mi++) {
        int row = mi * 16 + fr;
        const unsigned short* pa =
            (fq < 2) ? (Qs + row * 128 + (((h * 2 + fq) ^ (row & 7)) << 3))
                     : (const unsigned short*)&zchunk;
        af[mi] = *(const f16x8*)pa;
      }
#pragma unroll
      for (int ti = 0; ti < 4; ti++) {
        int trow = ti * 16 + fr;
        const unsigned short* pb =
            (fq < 2) ? (Ks2 + trow * 128 + (((h * 2 + fq) ^ (trow & 7)) << 3))
                     : (const unsigned short*)&zchunk;
        bf[ti] = *(const f16x8*)pb;
      }
#pragma unroll
      for (int mi = 0; mi < 4; mi++)
#pragma unroll
        for (int ti = 0; ti < 4; ti++)
          sc[mi][ti] = __builtin_amdgcn_mfma_f32_16x16x32_f16(
              af[mi], bf[ti], sc[mi][ti], 0, 0, 0);
    }
#pragma unroll
    for (int mi = 0; mi < 4; mi++) {
#pragma unroll
      for (int r = 0; r < 4; r++) {
        float m = -1e30f;
#pragma unroll
        for (int ti = 0; ti < 4; ti++) m = fmaxf(m, sc[mi][ti][r]);
        m = fmaxf(m, __shfl_xor(m, 1, 64));
        m = fmaxf(m, __shfl_xor(m, 2, 64));
        m = fmaxf(m, __shfl_xor(m, 4, 64));
        m = fmaxf(m, __shfl_xor(m, 8, 64));
        m *= 0.25f;
        float ss = 0.f;
#pragma unroll
        for (int ti = 0; ti < 4; ti++) {
          float p = expf(sc[mi][ti][r] * 0.25f - m);
          sc[mi][ti][r] = p;
          ss += p;
        }
        ss += __shfl_xor(ss, 1, 64);
        ss += __shfl_xor(ss, 2, 64);
        ss += __shfl_xor(ss, 4, 64);
        ss += __shfl_xor(ss, 8, 64);
        float inv = 1.f / ss;
        int prow = mi * 16 + fq * 4 + r;
#pragma unroll
        for (int ti = 0; ti < 4; ti++) {
          int t = ti * 16 + fr;
          Pb[prow * 64 + (((t >> 3) ^ (prow & 7)) << 3) + (t & 7)] =
              f2h(sc[mi][ti][r] * inv);
        }
      }
    }
    // PV
    f32x4 po[4];
#pragma unroll
    for (int i = 0; i < 4; i++) po[i] = (f32x4){0.f, 0.f, 0.f, 0.f};
#pragma unroll
    for (int ks2 = 0; ks2 < 2; ks2++) {
      f16x8 af[4], bf;
#pragma unroll
      for (int si = 0; si < 4; si++) {
        int prow = si * 16 + fr;
        int kq = (ks2 * 4 + fq) ^ (prow & 7);
        af[si] = *(const f16x8*)(Pb + prow * 64 + kq * 8);
      }
      {
        int vrow = h * 16 + fr;
        int kq = (ks2 * 4 + fq) ^ (vrow & 7);
        bf = *(const f16x8*)(VT + vrow * 64 + kq * 8);
      }
#pragma unroll
      for (int si = 0; si < 4; si++)
        po[si] = __builtin_amdgcn_mfma_f32_16x16x32_f16(af[si], bf, po[si],
                                                        0, 0, 0);
    }
#pragma unroll
    for (int si = 0; si < 4; si++)
#pragma unroll
      for (int r = 0; r < 4; r++) {
        int arow = si * 16 + fq * 4 + r;
        int ch = h * 16 + fr;
        AOs[arow * 128 + (((ch >> 3) ^ (arow & 7)) << 3) + (ch & 7)] =
            f2h(po[si][r]);
      }
  }
  __syncthreads();  // P3: AOs visible

  // ---- phase 4: v = x + ao @ Wout^T + bias ; LN1 -> Xs ----
  f16x8 w1f[4], w2f[4];  // FFN chunk-0 weights (prefetched below)
  {
    f16x8 bwo[4];
#pragma unroll
    for (int ks = 0; ks < 4; ks++)
      bwo[ks] = *(const f16x8*)(wout + (size_t)c * 128 + ks * 32 + fq * 8);
    f32x4 acc[4];
#pragma unroll
    for (int i = 0; i < 4; i++) acc[i] = (f32x4){0.f, 0.f, 0.f, 0.f};
#pragma unroll
    for (int ks = 0; ks < 4; ks++) {
      f16x8 af[4];
#pragma unroll
      for (int si = 0; si < 4; si++) {
        int row = si * 16 + fr;
        int kq = (ks * 4 + fq) ^ (row & 7);
        af[si] = *(const f16x8*)(AOs + row * 128 + kq * 8);
      }
#pragma unroll
      for (int si = 0; si < 4; si++)
        acc[si] = __builtin_amdgcn_mfma_f32_16x16x32_f16(af[si], bwo[ks],
                                                         acc[si], 0, 0, 0);
    }
    float bv = bout[c];
    float vv4[4][4];
    float sums[4][4], sqs[4][4];
#pragma unroll
    for (int si = 0; si < 4; si++)
#pragma unroll
      for (int r = 0; r < 4; r++) {
        int row = si * 16 + fq * 4 + r;
        float v = acc[si][r] + bv + xio[(size_t)(row * 256 + b) * 128 + c];
        vv4[si][r] = v;
        sums[si][r] = v;
        sqs[si][r] = v * v;
      }
#pragma unroll
    for (int d = 1; d < 16; d <<= 1) {
#pragma unroll
      for (int si = 0; si < 4; si++)
#pragma unroll
        for (int r = 0; r < 4; r++) {
          sums[si][r] += __shfl_xor(sums[si][r], d, 64);
          sqs[si][r] += __shfl_xor(sqs[si][r], d, 64);
        }
    }
    if (fr == 0) {
#pragma unroll
      for (int si = 0; si < 4; si++)
#pragma unroll
        for (int r = 0; r < 4; r++) {
          int row = si * 16 + fq * 4 + r;
          psum[w][row] = sums[si][r];
          psq[w][row] = sqs[si][r];
        }
    }
    // prefetch FFN chunk-0 weights (reg loads pipeline across barriers)
#pragma unroll
    for (int ks = 0; ks < 4; ks++) {
      w1f[ks] = *(const f16x8*)(w1 + (size_t)c * 128 + ks * 32 + fq * 8);
      w2f[ks] = *(const f16x8*)(w2 + (size_t)c * 2048 + ks * 32 + fq * 8);
    }
    __syncthreads();  // P4: psum visible
    if (tid < 64) {
      float S = 0.f, Q = 0.f;
#pragma unroll
      for (int ww = 0; ww < 8; ww++) { S += psum[ww][tid]; Q += psq[ww][tid]; }
      float m = S * (1.f / 128.f);
      float var = Q * (1.f / 128.f) - m * m;
      stats[tid] = make_float2(m, rsqrtf(var + 1e-5f));
    }
    __syncthreads();  // P5: stats visible
    float gl = ln1g[c], bl = ln1b[c];
#pragma unroll
    for (int si = 0; si < 4; si++)
#pragma unroll
      for (int r = 0; r < 4; r++) {
        int row = si * 16 + fq * 4 + r;
        float2 st2 = stats[row];
        float y = (vv4[si][r] - st2.x) * st2.y * gl + bl;
        Xs[row * 128 + (((c >> 3) ^ (row & 7)) << 3) + (c & 7)] = f2h(y);
      }
  }
  __syncthreads();  // P6: Xs (LN1 out) visible; Share (P) free

  // hoisted FFN x A-fragments
  f16x8 xfragF[4][4];
#pragma unroll
  for (int ks = 0; ks < 4; ks++)
#pragma unroll
    for (int mi = 0; mi < 4; mi++) {
      int row = mi * 16 + fr;
      int kq = (ks * 4 + fq) ^ (row & 7);
      xfragF[ks][mi] = *(const f16x8*)(Xs + row * 128 + kq * 8);
    }

  // ---- FFN: 16 chunks, 1 barrier each; Hs double-buffered in Share ----
  f32x4 acc2[4];
#pragma unroll
  for (int i = 0; i < 4; i++) acc2[i] = (f32x4){0.f, 0.f, 0.f, 0.f};

  for (int ch = 0; ch < 16; ch++) {
    // ff1: wave w -> hidden cols [w*16, w*16+16)
    f32x4 acc1[4];
#pragma unroll
    for (int i = 0; i < 4; i++) acc1[i] = (f32x4){0.f, 0.f, 0.f, 0.f};
#pragma unroll
    for (int ks = 0; ks < 4; ks++)
#pragma unroll
      for (int mi = 0; mi < 4; mi++)
        acc1[mi] = __builtin_amdgcn_mfma_f32_16x16x32_f16(
            xfragF[ks][mi], w1f[ks], acc1[mi], 0, 0, 0);
    // prefetch W1(ch+1) into regs
    if (ch < 15) {
#pragma unroll
      for (int ks = 0; ks < 4; ks++)
        w1f[ks] = *(const f16x8*)(w1 + (size_t)((ch + 1) * 128 + c) * 128 +
                                  ks * 32 + fq * 8);
    }
    // bias + relu -> Hs[ch&1]
    {
      unsigned short* Hc = Share + (ch & 1) * 8192;
      float bv = b1[ch * 128 + c];
#pragma unroll
      for (int mi = 0; mi < 4; mi++)
#pragma unroll
        for (int r = 0; r < 4; r++) {
          int row = mi * 16 + fq * 4 + r;
          Hc[row * 128 + (((c >> 3) ^ (row & 7)) << 3) + (c & 7)] =
              f2h(fmaxf(acc1[mi][r] + bv, 0.f));
        }
    }
    __syncthreads();  // Hs[ch&1] visible

    // ff2: wave w -> out cols [w*16, w*16+16)
    {
      const unsigned short* Hr = Share + (ch & 1) * 8192;
#pragma unroll
      for (int ks = 0; ks < 4; ks++) {
        f16x8 af[4];
#pragma unroll
        for (int si = 0; si < 4; si++) {
          int row = si * 16 + fr;
          int kq = (ks * 4 + fq) ^ (row & 7);
          af[si] = *(const f16x8*)(Hr + row * 128 + kq * 8);
        }
#pragma unroll
        for (int si = 0; si < 4; si++)
          acc2[si] = __builtin_amdgcn_mfma_f32_16x16x32_f16(af[si], w2f[ks],
                                                            acc2[si], 0, 0, 0);
      }
    }
    // prefetch W2(ch+1) into regs
    if (ch < 15) {
#pragma unroll
      for (int ks = 0; ks < 4; ks++)
        w2f[ks] = *(const f16x8*)(w2 + (size_t)c * 2048 + (ch + 1) * 128 +
                                  ks * 32 + fq * 8);
    }
  }

  // ---- FFN epilogue: +b2 + resid(Xs=LN1 out), LN2 -> xio + xbo ----
  {
    float bv = b2[c];
    float vv4[4][4];
    float sums[4][4], sqs[4][4];
#pragma unroll
    for (int si = 0; si < 4; si++)
#pragma unroll
      for (int r = 0; r < 4; r++) {
        int row = si * 16 + fq * 4 + r;
        float resid =
            h2f(Xs[row * 128 + (((c >> 3) ^ (row & 7)) << 3) + (c & 7)]);
        float v = acc2[si][r] + bv + resid;
        vv4[si][r] = v;
        sums[si][r] = v;
        sqs[si][r] = v * v;
      }
#pragma unroll
    for (int d = 1; d < 16; d <<= 1) {
#pragma unroll
      for (int si = 0; si < 4; si++)
#pragma unroll
        for (int r = 0; r < 4; r++) {
          sums[si][r] += __shfl_xor(sums[si][r], d, 64);
          sqs[si][r] += __shfl_xor(sqs[si][r], d, 64);
        }
    }
    if (fr == 0) {
#pragma unroll
      for (int si = 0; si < 4; si++)
#pragma unroll
        for (int r = 0; r < 4; r++) {
          int row = si * 16 + fq * 4 + r;
          psum[w][row] = sums[si][r];
          psq[w][row] = sqs[si][r];
        }
    }
    __syncthreads();
    if (tid < 64) {
      float S = 0.f, Q = 0.f;
#pragma unroll
      for (int ww = 0; ww < 8; ww++) { S += psum[ww][tid]; Q += psq[ww][tid]; }
      float m = S * (1.f / 128.f);
      float var = Q * (1.f / 128.f) - m * m;
      stats[tid] = make_float2(m, rsqrtf(var + 1e-5f));
    }
    __syncthreads();
    float gl = ln2g[c], bl = ln2b[c];
#pragma unroll
    for (int si = 0; si < 4; si++)
#pragma unroll
      for (int r = 0; r < 4; r++) {
        int row = si * 16 + fq * 4 + r;
        float2 st = stats[row];
        float y = (vv4[si][r] - st.x) * st.y * gl + bl;
        size_t o = (size_t)(row * 256 + b) * 128 + c;
        xio[o] = y;
        xbo[o] = f2h(y);
      }
  }
}

// ---------------------------------------------------------------------------
// Set2Set (6 steps) + memory LSTM + lin1 + lin3. One 512-thread block per
// segment. (512,1): 256-VGPR cap keeps the 48 uint4 gate weights resident.
// Input xb is f16 (direct copy into LDS).
// ---------------------------------------------------------------------------
__global__ __launch_bounds__(512, 1) void s2s_kernel(
    const unsigned short* __restrict__ xb,
    const unsigned short* __restrict__ wihh,
    const unsigned short* __restrict__ whhh,
    const float* __restrict__ bih, const float* __restrict__ bhh,
    const unsigned short* __restrict__ mwihh,
    const float* __restrict__ mbih, const float* __restrict__ mbhh,
    const float* __restrict__ l1w, const float* __restrict__ l1b,
    const float* __restrict__ l3w, const float* __restrict__ l3b,
    float* __restrict__ out) {
  __shared__ __align__(16) unsigned xl[256 * 65];
  __shared__ __align__(16) unsigned qu[128];
  __shared__ __align__(16) float cst[128];
  __shared__ __align__(16) float gates[512];
  __shared__ __align__(16) float red[256];
  __shared__ __align__(16) float aw[256];
  int s = blockIdx.x, t = threadIdx.x, lane = t & 63, w = t >> 6;

  uint4 wreg[32], ureg[16];
  {
    const uint4* wp = (const uint4*)(wihh + (size_t)t * 256);
#pragma unroll
    for (int i = 0; i < 32; i++) wreg[i] = wp[i];
    const uint4* up = (const uint4*)(whhh + (size_t)t * 128);
#pragma unroll
    for (int i = 0; i < 16; i++) ureg[i] = up[i];
  }

  const uint4* xs4 = (const uint4*)(xb + (size_t)s * 32768);
#pragma unroll
  for (int it = 0; it < 8; it++) {
    int f = it * 512 + t;
    uint4 v = xs4[f];
    int n = f >> 4, jc = (f & 15) * 4;
    unsigned* dst = xl + n * 65 + jc;
    dst[0] = v.x; dst[1] = v.y; dst[2] = v.z; dst[3] = v.w;
  }
  if (t < 128) cst[t] = 0.f;
  __syncthreads();

  const uint4* q4 = (const uint4*)qu;
  float bsum = bih[t] + bhh[t];

  for (int step = 0; step < 6; step++) {
    if (step > 0) {
      float a0 = 0.f, a1 = 0.f, a2 = 0.f, a3 = 0.f;
#pragma unroll
      for (int i = 0; i < 16; i++) {
        uint4 qv = q4[i];
        a0 = fdot2u(wreg[i].x, qv.x, a0);
        a1 = fdot2u(wreg[i].y, qv.y, a1);
        a2 = fdot2u(wreg[i].z, qv.z, a2);
        a3 = fdot2u(wreg[i].w, qv.w, a3);
        a0 = fdot2u(ureg[i].x, qv.x, a0);
        a1 = fdot2u(ureg[i].y, qv.y, a1);
        a2 = fdot2u(ureg[i].z, qv.z, a2);
        a3 = fdot2u(ureg[i].w, qv.w, a3);
      }
#pragma unroll
      for (int i = 16; i < 32; i++) {
        uint4 qv = q4[i];
        a0 = fdot2u(wreg[i].x, qv.x, a0);
        a1 = fdot2u(wreg[i].y, qv.y, a1);
        a2 = fdot2u(wreg[i].z, qv.z, a2);
        a3 = fdot2u(wreg[i].w, qv.w, a3);
      }
      gates[t] = bsum + ((a0 + a1) + (a2 + a3));
    } else {
      gates[t] = bsum;
    }
    __syncthreads();
    if (t < 128) {
      float ig = sigf(gates[t]), fg = sigf(gates[128 + t]);
      float gg = tanhf(gates[256 + t]), og = sigf(gates[384 + t]);
      float cn = fg * cst[t] + ig * gg;
      cst[t] = cn;
      float hn = og * tanhf(cn);
      float hp = __shfl_xor(hn, 1, 64);
      if ((t & 1) == 0) qu[t >> 1] = packh(hn, hp);
    }
    __syncthreads();
    if (step > 0) {
      int n = t >> 1, p = t & 1;
      const unsigned* xr = xl + n * 65 + p * 32;
      float e0 = 0.f, e1 = 0.f;
#pragma unroll 8
      for (int i = 0; i < 32; i += 2) {
        e0 = fdot2u(xr[i], qu[p * 32 + i], e0);
        e1 = fdot2u(xr[i + 1], qu[p * 32 + i + 1], e1);
      }
      float e = e0 + e1;
      e += __shfl_xor(e, 1, 64);
      if (p == 0) red[n] = e;
      __syncthreads();
      float v0 = red[lane], v1 = red[64 + lane];
      float v2 = red[128 + lane], v3 = red[192 + lane];
      float m = fmaxf(fmaxf(v0, v1), fmaxf(v2, v3));
#pragma unroll
      for (int d = 1; d < 64; d <<= 1) m = fmaxf(m, __shfl_xor(m, d, 64));
      float p0 = expf(v0 - m), p1 = expf(v1 - m);
      float p2 = expf(v2 - m), p3 = expf(v3 - m);
      float ss = p0 + p1 + p2 + p3;
#pragma unroll
      for (int d = 1; d < 64; d <<= 1) ss += __shfl_xor(ss, d, 64);
      float Sinv = 1.f / ss;
      if (w == 0) {
        aw[lane] = p0 * Sinv; aw[64 + lane] = p1 * Sinv;
        aw[128 + lane] = p2 * Sinv; aw[192 + lane] = p3 * Sinv;
      }
    } else {
      if (t < 256) aw[t] = 1.f / 256.f;
    }
    __syncthreads();
    {
      int d = t & 127, grp = t >> 7;
      const unsigned* xc = xl + grp * 64 * 65 + (d >> 1);
      int hi = d & 1;
      const float* ap = aw + grp * 64;
      float r = 0.f;
#pragma unroll 8
      for (int n2 = 0; n2 < 64; n2++) {
        unsigned u = xc[n2 * 65];
        r += ap[n2] * (hi ? hhi(u) : hlo(u));
      }
      gates[t] = r;
    }
    __syncthreads();
    if (t < 128) {
      float rd = gates[t] + gates[128 + t] + gates[256 + t] + gates[384 + t];
      float rp = __shfl_xor(rd, 1, 64);
      if ((t & 1) == 0) qu[64 + (t >> 1)] = packh(rd, rp);
    }
    __syncthreads();
  }
  {
    float a0 = 0.f, a1 = 0.f, a2 = 0.f, a3 = 0.f;
    const uint4* mp = (const uint4*)(mwihh + (size_t)t * 256);
#pragma unroll 8
    for (int i = 0; i < 32; i++) {
      uint4 wv = mp[i], qv = q4[i];
      a0 = fdot2u(wv.x, qv.x, a0);
      a1 = fdot2u(wv.y, qv.y, a1);
      a2 = fdot2u(wv.z, qv.z, a2);
      a3 = fdot2u(wv.w, qv.w, a3);
    }
    gates[t] = mbih[t] + mbhh[t] + ((a0 + a1) + (a2 + a3));
  }
  __syncthreads();
  if (t < 128) {
    float ig = sigf(gates[t]);
    float gg = tanhf(gates[256 + t]);
    float og = sigf(gates[384 + t]);
    float cx = ig * gg;
    float hx = og * tanhf(cx);
    cst[t] = hx;
    out[64 + s * 128 + t] = hx;
    out[64 + 8192 + s * 128 + t] = cx;
  }
  __syncthreads();
  if (t < 128) {
    float acc = l1b[t];
    const float4* w4 = (const float4*)(l1w + (size_t)t * 128);
    const float4* h4 = (const float4*)cst;
#pragma unroll 8
    for (int k = 0; k < 32; k++) {
      float4 a = w4[k], b = h4[k];
      acc += a.x * b.x + a.y * b.y + a.z * b.z + a.w * b.w;
    }
    red[t] = fmaxf(acc, 0.f) * l3w[t];
  } else if (t < 256) {
    red[t] = 0.f;
  }
  __syncthreads();
  for (int off = 128; off; off >>= 1) {
    if (t < off) red[t] += red[t + off];
    __syncthreads();
  }
  if (t == 0) out[s] = red[0] + l3b[0];
}

// ---------------------------------------------------------------------------
extern "C" void kernel_launch(void* const* d_in, const int* in_sizes, int n_in,
                              void* d_out, int out_size, void* d_ws,
                              size_t ws_size, hipStream_t stream) {
  const float* data       = (const float*)d_in[0];
  const float* lin0_w     = (const float*)d_in[1];
  const float* lin0_b     = (const float*)d_in[2];
  const float* attn_in_w  = (const float*)d_in[3];
  const float* attn_in_b  = (const float*)d_in[4];
  const float* attn_out_w = (const float*)d_in[5];
  const float* attn_out_b = (const float*)d_in[6];
  const float* ln1_g      = (const float*)d_in[7];
  const float* ln1_b      = (const float*)d_in[8];
  const float* ff_w1      = (const float*)d_in[9];
  const float* ff_b1      = (const float*)d_in[10];
  const float* ff_w2      = (const float*)d_in[11];
  const float* ff_b2      = (const float*)d_in[12];
  const float* ln2_g      = (const float*)d_in[13];
  const float* ln2_b      = (const float*)d_in[14];
  const float* s2s_wih    = (const float*)d_in[15];
  const float* s2s_whh    = (const float*)d_in[16];
  const float* s2s_bih    = (const float*)d_in[17];
  const float* s2s_bhh    = (const float*)d_in[18];
  const float* mem_wih    = (const float*)d_in[19];
  const float* mem_bih    = (const float*)d_in[21];
  const float* mem_bhh    = (const float*)d_in[22];
  const float* lin1_w     = (const float*)d_in[23];
  const float* lin1_b     = (const float*)d_in[24];
  const float* lin3_w     = (const float*)d_in[25];
  const float* lin3_b     = (const float*)d_in[26];
  float* out = (float*)d_out;

  char* p = (char*)d_ws;
  float* x = (float*)p;                      p += (size_t)16384 * 128 * 4;
  unsigned short* xb = (unsigned short*)p;   p += (size_t)16384 * 128 * 2;
  unsigned short* wqkv = (unsigned short*)p; p += (size_t)294912 * 2;
  unsigned short* wout = (unsigned short*)p; p += (size_t)98304 * 2;
  unsigned short* w1h = (unsigned short*)p;  p += (size_t)1572864 * 2;
  unsigned short* w2h = (unsigned short*)p;  p += (size_t)1572864 * 2;
  unsigned short* wihh = (unsigned short*)p; p += (size_t)131072 * 2;
  unsigned short* whhh = (unsigned short*)p; p += (size_t)65536 * 2;
  unsigned short* mwihh = (unsigned short*)p; p += (size_t)131072 * 2;

  convw_kernel<<<15104, 256, 0, stream>>>(
      attn_in_w, attn_out_w, ff_w1, ff_w2, s2s_wih, s2s_whh, mem_wih,
      wqkv, wout, w1h, w2h, wihh, whhh, mwihh);
  lin0_kernel<<<8192, 256, 0, stream>>>(data, lin0_w, lin0_b, x, xb);

  for (int l = 0; l < 6; l++) {
    layer_kernel<<<256, 512, 0, stream>>>(
        xb, wqkv + (size_t)l * 49152, attn_in_b + l * 384,
        wout + (size_t)l * 16384, attn_out_b + l * 128,
        ln1_g + l * 128, ln1_b + l * 128,
        w1h + (size_t)l * 262144, ff_b1 + l * 2048,
        w2h + (size_t)l * 262144, ff_b2 + l * 128,
        ln2_g + l * 128, ln2_b + l * 128, x, xb);
  }

  s2s_kernel<<<64, 512, 0, stream>>>(
      xb, wihh, whhh, s2s_bih, s2s_bhh,
      mwihh, mem_bih, mem_bhh, lin1_w, lin1_b, lin3_w, lin3_b, out);
}

// Round 13
// 485.895 us; speedup vs baseline: 1.3135x; 1.1856x over previous
//
#include <hip/hip_runtime.h>
#include <math.h>

// S=64 seq, B=256 atoms, N=16384, D=128, H=8, HD=16, DFF=2048, NL=6.
// R13 = R9 structure (best: per-layer dispatch, LDS-staged weights, no
// spills) + all-f16 datapath (f2h = 1 VALU inst vs f2bf's 4; mfma f16 same
// rate/layout as bf16). R11/R12's direct-reg weights abandoned: compiler
// pins VGPR=128 regardless of launch_bounds -> scratch spills.

typedef _Float16 __attribute__((ext_vector_type(8))) f16x8;
typedef __attribute__((ext_vector_type(4))) float f32x4;
typedef _Float16 __attribute__((ext_vector_type(2))) h16x2;

__device__ __forceinline__ unsigned short f2h(float f) {
  union { _Float16 h; unsigned short s; } x; x.h = (_Float16)f; return x.s;
}
__device__ __forceinline__ float h2f(unsigned short u) {
  union { unsigned short s; _Float16 h; } x; x.s = u; return (float)x.h;
}
__device__ __forceinline__ unsigned packh(float a, float b) {
  return (unsigned)f2h(a) | ((unsigned)f2h(b) << 16);
}
__device__ __forceinline__ float hlo(unsigned u) {
  union { unsigned short s; _Float16 h; } x; x.s = (unsigned short)(u & 0xffff);
  return (float)x.h;
}
__device__ __forceinline__ float hhi(unsigned u) {
  union { unsigned short s; _Float16 h; } x; x.s = (unsigned short)(u >> 16);
  return (float)x.h;
}
__device__ __forceinline__ float fdot2u(unsigned a, unsigned b, float c) {
#if __has_builtin(__builtin_amdgcn_fdot2)
  union U { unsigned u; h16x2 h; };
  U x, y; x.u = a; y.u = b;
  return __builtin_amdgcn_fdot2(x.h, y.h, c, false);
#else
  return c + hlo(a) * hlo(b) + hhi(a) * hhi(b);
#endif
}
__device__ __forceinline__ float sigf(float x) { return 1.f / (1.f + expf(-x)); }

// async 16B global->LDS; LDS base wave-uniform (+ lane*16 implicit).
__device__ __forceinline__ void gl2lds16(const void* g, void* l) {
  __builtin_amdgcn_global_load_lds(
      (const __attribute__((address_space(1))) unsigned int*)g,
      (__attribute__((address_space(3))) unsigned int*)l, 16, 0, 0);
}

// ---------------------------------------------------------------------------
// weight conversion: everything -> f16.
// aiw 294912 | aow 98304 | w1 1572864 | w2 1572864
// | wih 131072 | whh 65536 | mwih 131072   -> total 3866624
// ---------------------------------------------------------------------------
__global__ __launch_bounds__(256) void convw_kernel(
    const float* __restrict__ aiw, const float* __restrict__ aow,
    const float* __restrict__ w1, const float* __restrict__ w2,
    const float* __restrict__ wih, const float* __restrict__ whh,
    const float* __restrict__ mwih,
    unsigned short* __restrict__ o0, unsigned short* __restrict__ o1,
    unsigned short* __restrict__ o2, unsigned short* __restrict__ o3,
    unsigned short* __restrict__ o4, unsigned short* __restrict__ o5,
    unsigned short* __restrict__ o6) {
  int i = blockIdx.x * 256 + threadIdx.x;
  if (i < 294912) {
    o0[i] = f2h(aiw[i]);
  } else if (i < 393216) {
    int j = i - 294912; o1[j] = f2h(aow[j]);
  } else if (i < 1966080) {
    int j = i - 393216; o2[j] = f2h(w1[j]);
  } else if (i < 3538944) {
    int j = i - 1966080; o3[j] = f2h(w2[j]);
  } else if (i < 3670016) {
    int j = i - 3538944; o4[j] = f2h(wih[j]);
  } else if (i < 3735552) {
    int j = i - 3670016; o5[j] = f2h(whh[j]);
  } else {
    int j = i - 3735552; o6[j] = f2h(mwih[j]);
  }
}

// ---------------------------------------------------------------------------
// lin0: x = relu(data @ w^T + b), writes fp32 x and f16 xb
// ---------------------------------------------------------------------------
__global__ __launch_bounds__(256) void lin0_kernel(
    const float* __restrict__ data, const float* __restrict__ w,
    const float* __restrict__ b, float* __restrict__ x,
    unsigned short* __restrict__ xb) {
  int i = blockIdx.x * 256 + threadIdx.x;
  int n = i >> 7, d = i & 127;
  float v = b[d] + data[n * 3 + 0] * w[d * 3 + 0]
                 + data[n * 3 + 1] * w[d * 3 + 1]
                 + data[n * 3 + 2] * w[d * 3 + 2];
  v = fmaxf(v, 0.0f);
  x[i] = v;
  xb[i] = f2h(v);
}

// ---------------------------------------------------------------------------
// Fused transformer LAYER: block = atom b (256 blocks), 512 threads, 8 waves.
// R9 structure: LDS-staged weights (Ws), Hs XOR-swizzled, hoisted X frags.
// ---------------------------------------------------------------------------
__global__ __launch_bounds__(512) void layer_kernel(
    const unsigned short* __restrict__ xbg,
    const unsigned short* __restrict__ wqkv, const float* __restrict__ bqkv,
    const unsigned short* __restrict__ wout, const float* __restrict__ bout,
    const float* __restrict__ ln1g, const float* __restrict__ ln1b,
    const unsigned short* __restrict__ w1, const float* __restrict__ b1,
    const unsigned short* __restrict__ w2, const float* __restrict__ b2,
    const float* __restrict__ ln2g, const float* __restrict__ ln2b,
    float* __restrict__ xio, unsigned short* __restrict__ xbo) {
  __shared__ __align__(16) unsigned short Xs[64 * 128];   // 16 KB
  __shared__ __align__(16) unsigned short Ws[256 * 128];  // 64 KB
  __shared__ __align__(16) unsigned short U1[128 * 128];  // 32 KB
  __shared__ __align__(16) unsigned short U2[128 * 128];  // 32 KB
  __shared__ __align__(16) uint4 zchunk;
  __shared__ float psum[8][64], psq[8][64];
  __shared__ float2 stats[64];

  unsigned short* Qs = U1;            // 64x128
  unsigned short* Ks2 = U1 + 8192;    // 64x128
  unsigned short* VT = U2;            // 128x64
  unsigned short* AOs = U2 + 8192;    // 64x128
  unsigned short* Hs = U2;            // 64x128 swizzled (FFN)

  int tid = threadIdx.x, w = tid >> 6, lane = tid & 63;
  int b = blockIdx.x;
  int r4 = lane >> 4, cs = lane & 15;
  int fr = lane & 15, fq = lane >> 4;

  if (tid == 0) zchunk = make_uint4(0u, 0u, 0u, 0u);

  // ---- phase 0: stage x tile + Wq+Wk (wqkv rows 0..255) ----
#pragma unroll
  for (int i = 0; i < 2; i++) {
    int issue = w * 2 + i;
    int row = issue * 4 + r4;  // s index
    int g = cs ^ (row & 7);
    gl2lds16(xbg + (size_t)(row * 256 + b) * 128 + g * 8,
             (char*)Xs + issue * 1024);
  }
#pragma unroll
  for (int i = 0; i < 8; i++) {
    int issue = w * 8 + i;
    int row = issue * 4 + r4;
    int g = cs ^ (row & 7);
    gl2lds16(wqkv + (size_t)row * 128 + g * 8, (char*)Ws + issue * 1024);
  }
  __syncthreads();

  // hoisted x A-fragments (shared by phases 1 and 2)
  f16x8 xfragA[4][4];
#pragma unroll
  for (int ks = 0; ks < 4; ks++)
#pragma unroll
    for (int mi = 0; mi < 4; mi++) {
      int row = mi * 16 + fr;
      int kq = (ks * 4 + fq) ^ (row & 7);
      xfragA[ks][mi] = *(const f16x8*)(Xs + row * 128 + kq * 8);
    }

  // ---- phase 1: Q,K = x @ Wqk^T + bias -> Qs/Ks2 ----
  {
    f32x4 acc[4][2];
#pragma unroll
    for (int i = 0; i < 4; i++)
#pragma unroll
      for (int j = 0; j < 2; j++) acc[i][j] = (f32x4){0.f, 0.f, 0.f, 0.f};
#pragma unroll
    for (int ks = 0; ks < 4; ks++) {
      f16x8 bf[2];
#pragma unroll
      for (int ni = 0; ni < 2; ni++) {
        int wr = (w * 2 + ni) * 16 + fr;
        int kq = (ks * 4 + fq) ^ (wr & 7);
        bf[ni] = *(const f16x8*)(Ws + wr * 128 + kq * 8);
      }
#pragma unroll
      for (int mi = 0; mi < 4; mi++)
#pragma unroll
        for (int ni = 0; ni < 2; ni++)
          acc[mi][ni] = __builtin_amdgcn_mfma_f32_16x16x32_f16(
              xfragA[ks][mi], bf[ni], acc[mi][ni], 0, 0, 0);
    }
#pragma unroll
    for (int ni = 0; ni < 2; ni++) {
      int c = (w * 2 + ni) * 16 + fr;  // 0..255
      float bv = bqkv[c];
      unsigned short* dst = (c < 128) ? Qs : Ks2;
      int cc = c & 127;
#pragma unroll
      for (int mi = 0; mi < 4; mi++)
#pragma unroll
        for (int r = 0; r < 4; r++) {
          int row = mi * 16 + fq * 4 + r;
          dst[row * 128 + (((cc >> 3) ^ (row & 7)) << 3) + (cc & 7)] =
              f2h(acc[mi][ni][r] + bv);
        }
    }
  }
  __syncthreads();

  // ---- stage Wv (wqkv rows 256..383) into Ws rows 0..127 ----
#pragma unroll
  for (int i = 0; i < 4; i++) {
    int issue = w * 4 + i;
    int row = issue * 4 + r4;
    int g = cs ^ (row & 7);
    gl2lds16(wqkv + (size_t)(256 + row) * 128 + g * 8, (char*)Ws + issue * 1024);
  }
  __syncthreads();

  // ---- phase 2: V = x @ Wv^T + bias -> VT[feature][s] ----
  {
    f32x4 acc[4];
#pragma unroll
    for (int i = 0; i < 4; i++) acc[i] = (f32x4){0.f, 0.f, 0.f, 0.f};
#pragma unroll
    for (int ks = 0; ks < 4; ks++) {
      f16x8 bf;
      {
        int wr = w * 16 + fr;
        int kq = (ks * 4 + fq) ^ (wr & 7);
        bf = *(const f16x8*)(Ws + wr * 128 + kq * 8);
      }
#pragma unroll
      for (int mi = 0; mi < 4; mi++)
        acc[mi] = __builtin_amdgcn_mfma_f32_16x16x32_f16(xfragA[ks][mi], bf,
                                                         acc[mi], 0, 0, 0);
    }
    int f = w * 16 + fr;
    float bv = bqkv[256 + f];
#pragma unroll
    for (int mi = 0; mi < 4; mi++)
#pragma unroll
      for (int r = 0; r < 4; r++) {
        int srow = mi * 16 + fq * 4 + r;
        VT[f * 64 + (((srow >> 3) ^ (f & 7)) << 3) + (srow & 7)] =
            f2h(acc[mi][r] + bv);
      }
  }
  __syncthreads();

  // ---- phase 3: per-wave head attention (head h = w), P in Ws ----
  {
    int h = w;
    unsigned short* Pb = Ws + w * 4096;  // 8 KB per wave
    f32x4 sc[4][4];
#pragma unroll
    for (int i = 0; i < 4; i++)
#pragma unroll
      for (int j = 0; j < 4; j++) sc[i][j] = (f32x4){0.f, 0.f, 0.f, 0.f};
    {
      f16x8 af[4], bf[4];
#pragma unroll
      for (int mi = 0; mi < 4; mi++) {
        int row = mi * 16 + fr;
        const unsigned short* pa =
            (fq < 2) ? (Qs + row * 128 + (((h * 2 + fq) ^ (row & 7)) << 3))
                     : (const unsigned short*)&zchunk;
        af[mi] = *(const f16x8*)pa;
      }
#pragma unroll
      for (int ti = 0; ti < 4; ti++) {
        int trow = ti * 16 + fr;
        const unsigned short* pb =
            (fq < 2) ? (Ks2 + trow * 128 + (((h * 2 + fq) ^ (trow & 7)) << 3))
                     : (const unsigned short*)&zchunk;
        bf[ti] = *(const f16x8*)pb;
      }
#pragma unroll
      for (int mi = 0; mi < 4; mi++)
#pragma unroll
        for (int ti = 0; ti < 4; ti++)
          sc[mi][ti] = __builtin_amdgcn_mfma_f32_16x16x32_f16(
              af[mi], bf[ti], sc[mi][ti], 0, 0, 0);
    }
#pragma unroll
    for (int mi = 0; mi < 4; mi++) {
#pragma unroll
      for (int r = 0; r < 4; r++) {
        float m = -1e30f;
#pragma unroll
        for (int ti = 0; ti < 4; ti++) m = fmaxf(m, sc[mi][ti][r]);
        m = fmaxf(m, __shfl_xor(m, 1, 64));
        m = fmaxf(m, __shfl_xor(m, 2, 64));
        m = fmaxf(m, __shfl_xor(m, 4, 64));
        m = fmaxf(m, __shfl_xor(m, 8, 64));
        m *= 0.25f;
        float ss = 0.f;
#pragma unroll
        for (int ti = 0; ti < 4; ti++) {
          float p = expf(sc[mi][ti][r] * 0.25f - m);
          sc[mi][ti][r] = p;
          ss += p;
        }
        ss += __shfl_xor(ss, 1, 64);
        ss += __shfl_xor(ss, 2, 64);
        ss += __shfl_xor(ss, 4, 64);
        ss += __shfl_xor(ss, 8, 64);
        float inv = 1.f / ss;
        int prow = mi * 16 + fq * 4 + r;
#pragma unroll
        for (int ti = 0; ti < 4; ti++) {
          int t = ti * 16 + fr;
          Pb[prow * 64 + (((t >> 3) ^ (prow & 7)) << 3) + (t & 7)] =
              f2h(sc[mi][ti][r] * inv);
        }
      }
    }
    // PV
    f32x4 po[4];
#pragma unroll
    for (int i = 0; i < 4; i++) po[i] = (f32x4){0.f, 0.f, 0.f, 0.f};
#pragma unroll
    for (int ks2 = 0; ks2 < 2; ks2++) {
      f16x8 af[4], bf;
#pragma unroll
      for (int si = 0; si < 4; si++) {
        int prow = si * 16 + fr;
        int kq = (ks2 * 4 + fq) ^ (prow & 7);
        af[si] = *(const f16x8*)(Pb + prow * 64 + kq * 8);
      }
      {
        int vrow = h * 16 + fr;
        int kq = (ks2 * 4 + fq) ^ (vrow & 7);
        bf = *(const f16x8*)(VT + vrow * 64 + kq * 8);
      }
#pragma unroll
      for (int si = 0; si < 4; si++)
        po[si] = __builtin_amdgcn_mfma_f32_16x16x32_f16(af[si], bf, po[si],
                                                        0, 0, 0);
    }
#pragma unroll
    for (int si = 0; si < 4; si++)
#pragma unroll
      for (int r = 0; r < 4; r++) {
        int arow = si * 16 + fq * 4 + r;
        int c = h * 16 + fr;
        AOs[arow * 128 + (((c >> 3) ^ (arow & 7)) << 3) + (c & 7)] =
            f2h(po[si][r]);
      }
  }
  __syncthreads();

  // ---- stage Wout into Ws rows 0..127 ----
#pragma unroll
  for (int i = 0; i < 4; i++) {
    int issue = w * 4 + i;
    int row = issue * 4 + r4;
    int g = cs ^ (row & 7);
    gl2lds16(wout + (size_t)row * 128 + g * 8, (char*)Ws + issue * 1024);
  }
  __syncthreads();

  // ---- phase 4: v = x + ao @ Wout^T + bias ; LN1 -> Xs (f16) ----
  {
    f32x4 acc[4];
#pragma unroll
    for (int i = 0; i < 4; i++) acc[i] = (f32x4){0.f, 0.f, 0.f, 0.f};
#pragma unroll
    for (int ks = 0; ks < 4; ks++) {
      f16x8 af[4], bf;
#pragma unroll
      for (int si = 0; si < 4; si++) {
        int row = si * 16 + fr;
        int kq = (ks * 4 + fq) ^ (row & 7);
        af[si] = *(const f16x8*)(AOs + row * 128 + kq * 8);
      }
      {
        int wr = w * 16 + fr;
        int kq = (ks * 4 + fq) ^ (wr & 7);
        bf = *(const f16x8*)(Ws + wr * 128 + kq * 8);
      }
#pragma unroll
      for (int si = 0; si < 4; si++)
        acc[si] = __builtin_amdgcn_mfma_f32_16x16x32_f16(af[si], bf, acc[si],
                                                         0, 0, 0);
    }
    int c = w * 16 + fr;
    float bv = bout[c];
    float vv4[4][4];
    float sums[4][4], sqs[4][4];
#pragma unroll
    for (int si = 0; si < 4; si++)
#pragma unroll
      for (int r = 0; r < 4; r++) {
        int row = si * 16 + fq * 4 + r;
        float v = acc[si][r] + bv + xio[(size_t)(row * 256 + b) * 128 + c];
        vv4[si][r] = v;
        sums[si][r] = v;
        sqs[si][r] = v * v;
      }
#pragma unroll
    for (int d = 1; d < 16; d <<= 1) {
#pragma unroll
      for (int si = 0; si < 4; si++)
#pragma unroll
        for (int r = 0; r < 4; r++) {
          sums[si][r] += __shfl_xor(sums[si][r], d, 64);
          sqs[si][r] += __shfl_xor(sqs[si][r], d, 64);
        }
    }
    if (fr == 0) {
#pragma unroll
      for (int si = 0; si < 4; si++)
#pragma unroll
        for (int r = 0; r < 4; r++) {
          int row = si * 16 + fq * 4 + r;
          psum[w][row] = sums[si][r];
          psq[w][row] = sqs[si][r];
        }
    }
    __syncthreads();  // A: phase-4 mfma done everywhere -> Ws/U1 reusable

    // FFN prologue staging: W1(0)->Ws[0], W2(0)->U1 (drains at barrier B)
#pragma unroll
    for (int i = 0; i < 4; i++) {
      int issue = w * 4 + i;
      int row = issue * 4 + r4;
      int g = cs ^ (row & 7);
      gl2lds16(w1 + (size_t)row * 128 + g * 8, (char*)Ws + issue * 1024);
      gl2lds16(w2 + (size_t)row * 2048 + g * 8, (char*)U1 + issue * 1024);
    }
    if (tid < 64) {
      float S = 0.f, Q = 0.f;
#pragma unroll
      for (int ww = 0; ww < 8; ww++) { S += psum[ww][tid]; Q += psq[ww][tid]; }
      float m = S * (1.f / 128.f);
      float var = Q * (1.f / 128.f) - m * m;
      stats[tid] = make_float2(m, rsqrtf(var + 1e-5f));
    }
    __syncthreads();  // B
    float gl = ln1g[c], bl = ln1b[c];
#pragma unroll
    for (int si = 0; si < 4; si++)
#pragma unroll
      for (int r = 0; r < 4; r++) {
        int row = si * 16 + fq * 4 + r;
        float2 st2 = stats[row];
        float y = (vv4[si][r] - st2.x) * st2.y * gl + bl;
        Xs[row * 128 + (((c >> 3) ^ (row & 7)) << 3) + (c & 7)] = f2h(y);
      }
  }
  __syncthreads();  // C: Xs (LN1 output) published; W1(0)/W2(0) drained

  // hoisted FFN x A-fragments (invariant across all 16 chunks)
  f16x8 xfragF[4][4];
#pragma unroll
  for (int ks = 0; ks < 4; ks++)
#pragma unroll
    for (int mi = 0; mi < 4; mi++) {
      int row = mi * 16 + fr;
      int kq = (ks * 4 + fq) ^ (row & 7);
      xfragF[ks][mi] = *(const f16x8*)(Xs + row * 128 + kq * 8);
    }

  // ---- FFN chunk loop: 16 chunks of 128 hidden, 8 waves x 16 cols ----
  f32x4 acc2[4];
#pragma unroll
  for (int i = 0; i < 4; i++) acc2[i] = (f32x4){0.f, 0.f, 0.f, 0.f};

  for (int c = 0; c < 16; c++) {
    const unsigned short* W1cur = Ws + (c & 1) * 16384;
    // ff1: wave w -> hidden cols [w*16, w*16+16)
    f32x4 acc1[4];
#pragma unroll
    for (int i = 0; i < 4; i++) acc1[i] = (f32x4){0.f, 0.f, 0.f, 0.f};
#pragma unroll
    for (int ks = 0; ks < 4; ks++) {
      f16x8 bf;
      {
        int row = w * 16 + fr;
        int kq = (ks * 4 + fq) ^ (row & 7);
        bf = *(const f16x8*)(W1cur + row * 128 + kq * 8);
      }
#pragma unroll
      for (int mi = 0; mi < 4; mi++)
        acc1[mi] = __builtin_amdgcn_mfma_f32_16x16x32_f16(xfragF[ks][mi], bf,
                                                          acc1[mi], 0, 0, 0);
    }
    // prefetch W1(c+1)
    if (c < 15) {
#pragma unroll
      for (int i = 0; i < 4; i++) {
        int issue = w * 4 + i;
        int row = issue * 4 + r4;
        int g = cs ^ (row & 7);
        gl2lds16(w1 + (size_t)((c + 1) * 128 + row) * 128 + g * 8,
                 (char*)Ws + ((c + 1) & 1) * 32768 + issue * 1024);
      }
    }
    // bias + relu -> Hs (f16, XOR-swizzled 128-stride)
    {
      int col = w * 16 + fr;
      float bv = b1[c * 128 + col];
#pragma unroll
      for (int mi = 0; mi < 4; mi++)
#pragma unroll
        for (int r = 0; r < 4; r++) {
          int row = mi * 16 + fq * 4 + r;
          Hs[row * 128 + (((col >> 3) ^ (row & 7)) << 3) + (col & 7)] =
              f2h(fmaxf(acc1[mi][r] + bv, 0.f));
        }
    }
    __syncthreads();  // B1: Hs visible; drains W2(c)/W1(c+1)

    // ff2: wave w -> out cols [w*16, w*16+16)
#pragma unroll
    for (int ks = 0; ks < 4; ks++) {
      f16x8 af[4], bf;
#pragma unroll
      for (int si = 0; si < 4; si++) {
        int row = si * 16 + fr;
        int kq = (ks * 4 + fq) ^ (row & 7);
        af[si] = *(const f16x8*)(Hs + row * 128 + kq * 8);
      }
      {
        int row = w * 16 + fr;
        int kq = (ks * 4 + fq) ^ (row & 7);
        bf = *(const f16x8*)(U1 + row * 128 + kq * 8);
      }
#pragma unroll
      for (int si = 0; si < 4; si++)
        acc2[si] = __builtin_amdgcn_mfma_f32_16x16x32_f16(af[si], bf, acc2[si],
                                                          0, 0, 0);
    }
    __syncthreads();  // B2: U1/Hs reusable
    // stage W2(c+1) (overlaps next ff1)
    if (c < 15) {
#pragma unroll
      for (int i = 0; i < 4; i++) {
        int issue = w * 4 + i;
        int row = issue * 4 + r4;
        int g = cs ^ (row & 7);
        gl2lds16(w2 + (size_t)row * 2048 + (c + 1) * 128 + g * 8,
                 (char*)U1 + issue * 1024);
      }
    }
  }

  // ---- FFN epilogue: +b2 + residual (from Xs), LN2, write global ----
  {
    int c = w * 16 + fr;
    float bv = b2[c];
    float vv4[4][4];
    float sums[4][4], sqs[4][4];
#pragma unroll
    for (int si = 0; si < 4; si++)
#pragma unroll
      for (int r = 0; r < 4; r++) {
        int row = si * 16 + fq * 4 + r;
        float resid =
            h2f(Xs[row * 128 + (((c >> 3) ^ (row & 7)) << 3) + (c & 7)]);
        float v = acc2[si][r] + bv + resid;
        vv4[si][r] = v;
        sums[si][r] = v;
        sqs[si][r] = v * v;
      }
#pragma unroll
    for (int d = 1; d < 16; d <<= 1) {
#pragma unroll
      for (int si = 0; si < 4; si++)
#pragma unroll
        for (int r = 0; r < 4; r++) {
          sums[si][r] += __shfl_xor(sums[si][r], d, 64);
          sqs[si][r] += __shfl_xor(sqs[si][r], d, 64);
        }
    }
    if (fr == 0) {
#pragma unroll
      for (int si = 0; si < 4; si++)
#pragma unroll
        for (int r = 0; r < 4; r++) {
          int row = si * 16 + fq * 4 + r;
          psum[w][row] = sums[si][r];
          psq[w][row] = sqs[si][r];
        }
    }
    __syncthreads();
    if (tid < 64) {
      float S = 0.f, Q = 0.f;
#pragma unroll
      for (int ww = 0; ww < 8; ww++) { S += psum[ww][tid]; Q += psq[ww][tid]; }
      float m = S * (1.f / 128.f);
      float var = Q * (1.f / 128.f) - m * m;
      stats[tid] = make_float2(m, rsqrtf(var + 1e-5f));
    }
    __syncthreads();
    float gl = ln2g[c], bl = ln2b[c];
#pragma unroll
    for (int si = 0; si < 4; si++)
#pragma unroll
      for (int r = 0; r < 4; r++) {
        int row = si * 16 + fq * 4 + r;
        float2 st = stats[row];
        float y = (vv4[si][r] - st.x) * st.y * gl + bl;
        size_t o = (size_t)(row * 256 + b) * 128 + c;
        xio[o] = y;
        xbo[o] = f2h(y);
      }
  }
}

// ---------------------------------------------------------------------------
// Set2Set (6 steps) + memory LSTM + lin1 + lin3. One 512-thread block per
// segment. Input xb is f16 (direct copy into LDS).
// ---------------------------------------------------------------------------
__global__ __launch_bounds__(512, 1) void s2s_kernel(
    const unsigned short* __restrict__ xb,
    const unsigned short* __restrict__ wihh,
    const unsigned short* __restrict__ whhh,
    const float* __restrict__ bih, const float* __restrict__ bhh,
    const unsigned short* __restrict__ mwihh,
    const float* __restrict__ mbih, const float* __restrict__ mbhh,
    const float* __restrict__ l1w, const float* __restrict__ l1b,
    const float* __restrict__ l3w, const float* __restrict__ l3b,
    float* __restrict__ out) {
  __shared__ __align__(16) unsigned xl[256 * 65];
  __shared__ __align__(16) unsigned qu[128];
  __shared__ __align__(16) float cst[128];
  __shared__ __align__(16) float gates[512];
  __shared__ __align__(16) float red[256];
  __shared__ __align__(16) float aw[256];
  int s = blockIdx.x, t = threadIdx.x, lane = t & 63, w = t >> 6;

  uint4 wreg[32], ureg[16];
  {
    const uint4* wp = (const uint4*)(wihh + (size_t)t * 256);
#pragma unroll
    for (int i = 0; i < 32; i++) wreg[i] = wp[i];
    const uint4* up = (const uint4*)(whhh + (size_t)t * 128);
#pragma unroll
    for (int i = 0; i < 16; i++) ureg[i] = up[i];
  }

  const uint4* xs4 = (const uint4*)(xb + (size_t)s * 32768);
#pragma unroll
  for (int it = 0; it < 8; it++) {
    int f = it * 512 + t;
    uint4 v = xs4[f];
    int n = f >> 4, jc = (f & 15) * 4;
    unsigned* dst = xl + n * 65 + jc;
    dst[0] = v.x; dst[1] = v.y; dst[2] = v.z; dst[3] = v.w;
  }
  if (t < 128) cst[t] = 0.f;
  __syncthreads();

  const uint4* q4 = (const uint4*)qu;
  float bsum = bih[t] + bhh[t];

  for (int step = 0; step < 6; step++) {
    if (step > 0) {
      float a0 = 0.f, a1 = 0.f, a2 = 0.f, a3 = 0.f;
#pragma unroll
      for (int i = 0; i < 16; i++) {
        uint4 qv = q4[i];
        a0 = fdot2u(wreg[i].x, qv.x, a0);
        a1 = fdot2u(wreg[i].y, qv.y, a1);
        a2 = fdot2u(wreg[i].z, qv.z, a2);
        a3 = fdot2u(wreg[i].w, qv.w, a3);
        a0 = fdot2u(ureg[i].x, qv.x, a0);
        a1 = fdot2u(ureg[i].y, qv.y, a1);
        a2 = fdot2u(ureg[i].z, qv.z, a2);
        a3 = fdot2u(ureg[i].w, qv.w, a3);
      }
#pragma unroll
      for (int i = 16; i < 32; i++) {
        uint4 qv = q4[i];
        a0 = fdot2u(wreg[i].x, qv.x, a0);
        a1 = fdot2u(wreg[i].y, qv.y, a1);
        a2 = fdot2u(wreg[i].z, qv.z, a2);
        a3 = fdot2u(wreg[i].w, qv.w, a3);
      }
      gates[t] = bsum + ((a0 + a1) + (a2 + a3));
    } else {
      gates[t] = bsum;
    }
    __syncthreads();
    if (t < 128) {
      float ig = sigf(gates[t]), fg = sigf(gates[128 + t]);
      float gg = tanhf(gates[256 + t]), og = sigf(gates[384 + t]);
      float cn = fg * cst[t] + ig * gg;
      cst[t] = cn;
      float hn = og * tanhf(cn);
      float hp = __shfl_xor(hn, 1, 64);
      if ((t & 1) == 0) qu[t >> 1] = packh(hn, hp);
    }
    __syncthreads();
    if (step > 0) {
      int n = t >> 1, p = t & 1;
      const unsigned* xr = xl + n * 65 + p * 32;
      float e0 = 0.f, e1 = 0.f;
#pragma unroll 8
      for (int i = 0; i < 32; i += 2) {
        e0 = fdot2u(xr[i], qu[p * 32 + i], e0);
        e1 = fdot2u(xr[i + 1], qu[p * 32 + i + 1], e1);
      }
      float e = e0 + e1;
      e += __shfl_xor(e, 1, 64);
      if (p == 0) red[n] = e;
      __syncthreads();
      float v0 = red[lane], v1 = red[64 + lane];
      float v2 = red[128 + lane], v3 = red[192 + lane];
      float m = fmaxf(fmaxf(v0, v1), fmaxf(v2, v3));
#pragma unroll
      for (int d = 1; d < 64; d <<= 1) m = fmaxf(m, __shfl_xor(m, d, 64));
      float p0 = expf(v0 - m), p1 = expf(v1 - m);
      float p2 = expf(v2 - m), p3 = expf(v3 - m);
      float ss = p0 + p1 + p2 + p3;
#pragma unroll
      for (int d = 1; d < 64; d <<= 1) ss += __shfl_xor(ss, d, 64);
      float Sinv = 1.f / ss;
      if (w == 0) {
        aw[lane] = p0 * Sinv; aw[64 + lane] = p1 * Sinv;
        aw[128 + lane] = p2 * Sinv; aw[192 + lane] = p3 * Sinv;
      }
    } else {
      if (t < 256) aw[t] = 1.f / 256.f;
    }
    __syncthreads();
    {
      int d = t & 127, grp = t >> 7;
      const unsigned* xc = xl + grp * 64 * 65 + (d >> 1);
      int hi = d & 1;
      const float* ap = aw + grp * 64;
      float r = 0.f;
#pragma unroll 8
      for (int n2 = 0; n2 < 64; n2++) {
        unsigned u = xc[n2 * 65];
        r += ap[n2] * (hi ? hhi(u) : hlo(u));
      }
      gates[t] = r;
    }
    __syncthreads();
    if (t < 128) {
      float rd = gates[t] + gates[128 + t] + gates[256 + t] + gates[384 + t];
      float rp = __shfl_xor(rd, 1, 64);
      if ((t & 1) == 0) qu[64 + (t >> 1)] = packh(rd, rp);
    }
    __syncthreads();
  }
  {
    float a0 = 0.f, a1 = 0.f, a2 = 0.f, a3 = 0.f;
    const uint4* mp = (const uint4*)(mwihh + (size_t)t * 256);
#pragma unroll 8
    for (int i = 0; i < 32; i++) {
      uint4 wv = mp[i], qv = q4[i];
      a0 = fdot2u(wv.x, qv.x, a0);
      a1 = fdot2u(wv.y, qv.y, a1);
      a2 = fdot2u(wv.z, qv.z, a2);
      a3 = fdot2u(wv.w, qv.w, a3);
    }
    gates[t] = mbih[t] + mbhh[t] + ((a0 + a1) + (a2 + a3));
  }
  __syncthreads();
  if (t < 128) {
    float ig = sigf(gates[t]);
    float gg = tanhf(gates[256 + t]);
    float og = sigf(gates[384 + t]);
    float cx = ig * gg;
    float hx = og * tanhf(cx);
    cst[t] = hx;
    out[64 + s * 128 + t] = hx;
    out[64 + 8192 + s * 128 + t] = cx;
  }
  __syncthreads();
  if (t < 128) {
    float acc = l1b[t];
    const float4* w4 = (const float4*)(l1w + (size_t)t * 128);
    const float4* h4 = (const float4*)cst;
#pragma unroll 8
    for (int k = 0; k < 32; k++) {
      float4 a = w4[k], b = h4[k];
      acc += a.x * b.x + a.y * b.y + a.z * b.z + a.w * b.w;
    }
    red[t] = fmaxf(acc, 0.f) * l3w[t];
  } else if (t < 256) {
    red[t] = 0.f;
  }
  __syncthreads();
  for (int off = 128; off; off >>= 1) {
    if (t < off) red[t] += red[t + off];
    __syncthreads();
  }
  if (t == 0) out[s] = red[0] + l3b[0];
}

// ---------------------------------------------------------------------------
extern "C" void kernel_launch(void* const* d_in, const int* in_sizes, int n_in,
                              void* d_out, int out_size, void* d_ws,
                              size_t ws_size, hipStream_t stream) {
  const float* data       = (const float*)d_in[0];
  const float* lin0_w     = (const float*)d_in[1];
  const float* lin0_b     = (const float*)d_in[2];
  const float* attn_in_w  = (const float*)d_in[3];
  const float* attn_in_b  = (const float*)d_in[4];
  const float* attn_out_w = (const float*)d_in[5];
  const float* attn_out_b = (const float*)d_in[6];
  const float* ln1_g      = (const float*)d_in[7];
  const float* ln1_b      = (const float*)d_in[8];
  const float* ff_w1      = (const float*)d_in[9];
  const float* ff_b1      = (const float*)d_in[10];
  const float* ff_w2      = (const float*)d_in[11];
  const float* ff_b2      = (const float*)d_in[12];
  const float* ln2_g      = (const float*)d_in[13];
  const float* ln2_b      = (const float*)d_in[14];
  const float* s2s_wih    = (const float*)d_in[15];
  const float* s2s_whh    = (const float*)d_in[16];
  const float* s2s_bih    = (const float*)d_in[17];
  const float* s2s_bhh    = (const float*)d_in[18];
  const float* mem_wih    = (const float*)d_in[19];
  const float* mem_bih    = (const float*)d_in[21];
  const float* mem_bhh    = (const float*)d_in[22];
  const float* lin1_w     = (const float*)d_in[23];
  const float* lin1_b     = (const float*)d_in[24];
  const float* lin3_w     = (const float*)d_in[25];
  const float* lin3_b     = (const float*)d_in[26];
  float* out = (float*)d_out;

  char* p = (char*)d_ws;
  float* x = (float*)p;                      p += (size_t)16384 * 128 * 4;
  unsigned short* xb = (unsigned short*)p;   p += (size_t)16384 * 128 * 2;
  unsigned short* wqkv = (unsigned short*)p; p += (size_t)294912 * 2;
  unsigned short* wout = (unsigned short*)p; p += (size_t)98304 * 2;
  unsigned short* w1h = (unsigned short*)p;  p += (size_t)1572864 * 2;
  unsigned short* w2h = (unsigned short*)p;  p += (size_t)1572864 * 2;
  unsigned short* wihh = (unsigned short*)p; p += (size_t)131072 * 2;
  unsigned short* whhh = (unsigned short*)p; p += (size_t)65536 * 2;
  unsigned short* mwihh = (unsigned short*)p; p += (size_t)131072 * 2;

  convw_kernel<<<15104, 256, 0, stream>>>(
      attn_in_w, attn_out_w, ff_w1, ff_w2, s2s_wih, s2s_whh, mem_wih,
      wqkv, wout, w1h, w2h, wihh, whhh, mwihh);
  lin0_kernel<<<8192, 256, 0, stream>>>(data, lin0_w, lin0_b, x, xb);

  for (int l = 0; l < 6; l++) {
    layer_kernel<<<256, 512, 0, stream>>>(
        xb, wqkv + (size_t)l * 49152, attn_in_b + l * 384,
        wout + (size_t)l * 16384, attn_out_b + l * 128,
        ln1_g + l * 128, ln1_b + l * 128,
        w1h + (size_t)l * 262144, ff_b1 + l * 2048,
        w2h + (size_t)l * 262144, ff_b2 + l * 128,
        ln2_g + l * 128, ln2_b + l * 128, x, xb);
  }

  s2s_kernel<<<64, 512, 0, stream>>>(
      xb, wihh, whhh, s2s_bih, s2s_bhh,
      mwihh, mem_bih, mem_bhh, lin1_w, lin1_b, lin3_w, lin3_b, out);
}